// Round 6
// baseline (1947.130 us; speedup 1.0000x reference)
//
#include <hip/hip_runtime.h>
#include <hip/hip_bf16.h>
#include <math.h>

// ---------------------------------------------------------------------------
// Types
// ---------------------------------------------------------------------------
typedef __bf16 bf16_t;
typedef __bf16 bf16x8 __attribute__((ext_vector_type(8)));
typedef __bf16 bf16x4 __attribute__((ext_vector_type(4)));
typedef float  f32x4  __attribute__((ext_vector_type(4)));

#define MFMA_BF16(a, b, c) __builtin_amdgcn_mfma_f32_16x16x32_bf16((a), (b), (c), 0, 0, 0)

typedef const void __attribute__((address_space(1)))* gas_ptr;
typedef void       __attribute__((address_space(3)))* las_ptr;

__device__ __forceinline__ void gload_lds16(const void* g, void* l) {
  // global -> LDS direct, 16B per lane. LDS dest is wave-uniform base + lane*16.
  __builtin_amdgcn_global_load_lds((gas_ptr)g, (las_ptr)l, 16, 0, 0);
}

// ---------------------------------------------------------------------------
// Model constants
// ---------------------------------------------------------------------------
static constexpr int B_ = 4, S_ = 1024, D_ = 1024, HF_ = 4096, V_ = 32000;
static constexpr int NH_ = 16, HD_ = 64;
static constexpr int TOK_ = B_ * S_;  // 4096

// ---------------------------------------------------------------------------
// fp32 -> bf16 conversion (vectorized x4)
// ---------------------------------------------------------------------------
__global__ __launch_bounds__(256) void cvt_f32_bf16(const float* __restrict__ in,
                                                    bf16_t* __restrict__ out, int n4) {
  int i = blockIdx.x * 256 + threadIdx.x;
  if (i < n4) {
    float4 v = ((const float4*)in)[i];
    bf16x4 o;
    o[0] = (bf16_t)v.x; o[1] = (bf16_t)v.y; o[2] = (bf16_t)v.z; o[3] = (bf16_t)v.w;
    ((bf16x4*)out)[i] = o;
  }
}

// ---------------------------------------------------------------------------
// Sinusoidal positional encoding table
// ---------------------------------------------------------------------------
__global__ __launch_bounds__(256) void pe_kernel(float* __restrict__ pe) {
  const int s = blockIdx.x;
  for (int i = threadIdx.x; i < D_ / 2; i += 256) {
    float div = expf((2.0f * (float)i) * (-9.210340371976184f / (float)D_)); // ln(10000)
    float a = (float)s * div;
    pe[(size_t)s * D_ + 2 * i]     = sinf(a);
    pe[(size_t)s * D_ + 2 * i + 1] = cosf(a);
  }
}

// ---------------------------------------------------------------------------
// Embedding: h[t][d] = emb_W[x[t]][d] * 32 + pe[t % S][d]
// ---------------------------------------------------------------------------
__global__ __launch_bounds__(256) void embed_kernel(const int* __restrict__ x,
                                                    const float* __restrict__ embW,
                                                    const float* __restrict__ pe,
                                                    float* __restrict__ h) {
  int i = blockIdx.x * 256 + threadIdx.x;
  int token = i >> 8;
  int c4 = i & 255;
  int idx = x[token];
  float4 e = ((const float4*)(embW + (size_t)idx * D_))[c4];
  float4 p = ((const float4*)(pe + (size_t)(token & (S_ - 1)) * D_))[c4];
  float4 o;
  o.x = e.x * 32.0f + p.x; o.y = e.y * 32.0f + p.y;
  o.z = e.z * 32.0f + p.z; o.w = e.w * 32.0f + p.w;
  ((float4*)(h + (size_t)token * D_))[c4] = o;
}

// ---------------------------------------------------------------------------
// a_in = h + LayerNorm(h)*g + b   -> bf16
// ---------------------------------------------------------------------------
__global__ __launch_bounds__(256) void ln_res_kernel(const float* __restrict__ h,
                                                     const float* __restrict__ gamma,
                                                     const float* __restrict__ beta,
                                                     bf16_t* __restrict__ out) {
  const int row = blockIdx.x;
  const int tid = threadIdx.x;
  const float4 v = ((const float4*)(h + (size_t)row * D_))[tid];
  float s  = v.x + v.y + v.z + v.w;
  float s2 = v.x * v.x + v.y * v.y + v.z * v.z + v.w * v.w;
#pragma unroll
  for (int m = 1; m < 64; m <<= 1) {
    s  += __shfl_xor(s, m, 64);
    s2 += __shfl_xor(s2, m, 64);
  }
  __shared__ float red[2][4];
  const int wave = tid >> 6, lane = tid & 63;
  if (lane == 0) { red[0][wave] = s; red[1][wave] = s2; }
  __syncthreads();
  s  = red[0][0] + red[0][1] + red[0][2] + red[0][3];
  s2 = red[1][0] + red[1][1] + red[1][2] + red[1][3];
  const float mu   = s * (1.0f / D_);
  const float rstd = rsqrtf(s2 * (1.0f / D_) - mu * mu + 1e-5f);
  const float4 g4 = ((const float4*)gamma)[tid];
  const float4 b4 = ((const float4*)beta)[tid];
  bf16x4 o;
  o[0] = (bf16_t)(v.x + (v.x - mu) * rstd * g4.x + b4.x);
  o[1] = (bf16_t)(v.y + (v.y - mu) * rstd * g4.y + b4.y);
  o[2] = (bf16_t)(v.z + (v.z - mu) * rstd * g4.z + b4.z);
  o[3] = (bf16_t)(v.w + (v.w - mu) * rstd * g4.w + b4.w);
  ((bf16x4*)(out + (size_t)row * D_))[tid] = o;
}

// ---------------------------------------------------------------------------
// Occupancy-first GEMM: C[4096,N] = A[4096,K] @ W[N,K]^T  (K mult of 32)
// BM=256, BN=128, BK=32, 8 waves (4M x 2N), per-wave 64x64 (acc[4][4]=64 regs)
// LDS 48 KB (2 bufs x 24 KB) + launch_bounds(512,4) => regs<=128 =>
// 2 blocks/CU: sibling block covers the vmcnt(0) drain + epilogue bursts
// (m97 mechanism). One barrier per tile, setprio around MFMA.
// Swizzle: 64B rows, col ^ ((row>>1)&3)<<4 (measured 0 conflicts), applied
// as involution (pre-swizzled global src, linear LDS dest, swizzled ds_read).
// M-fastest block order (16 consecutive blocks share one B panel) +
// bijective XCD swizzle (grid % 8 == 0).
// NKC: split-K chunks (for N=1024 shapes) - partials via fp32 atomicAdd.
// Epilogues: 0 QKV-scatter, 1 atomicAdd resid, 2 bias+relu->bf16,
//            3 atomicAdd resid+bias(kc==0), 4 bias->f32.
// ---------------------------------------------------------------------------
template <int EPI, int NKC>
__global__ __launch_bounds__(512, 4) void gemm_pipe(
    const bf16_t* __restrict__ A, const bf16_t* __restrict__ W, int N, int K,
    float* __restrict__ fout, const float* __restrict__ bias, bf16_t* __restrict__ bout,
    bf16_t* __restrict__ qb, bf16_t* __restrict__ kb, bf16_t* __restrict__ vtb) {
  __shared__ char lds[49152];  // 2 bufs x (A 16 KB | B 8 KB)

  const int tid = threadIdx.x;
  const int wave = tid >> 6, lane = tid & 63;
  const int row16 = lane & 15, kgrp = lane >> 4;
  const int wm = wave >> 1, wn = wave & 1;  // 4M x 2N wave grid

  // block swizzle: XCD-bijective (grid % 8 == 0), then M-fastest (16 M-tiles)
  const int nb = gridDim.x;
  const int logical = (blockIdx.x & 7) * (nb >> 3) + (blockIdx.x >> 3);
  const int m0 = (logical & 15) << 8;
  const int rest = logical >> 4;
  const int kc = (NKC > 1) ? (rest & (NKC - 1)) : 0;
  const int n0 = (NKC > 1 ? rest / NKC : rest) << 7;
  const int KC = K / NKC;
  const size_t K2 = (size_t)K * 2;

  // staging: thread covers row srow (+128 for A round 1), 16 B at
  // inverse-swizzled byte col within the 64 B row
  const int srow = tid >> 2;
  const int scol = ((tid & 3) * 16) ^ (((srow >> 1) & 3) << 4);
  const char* pA0 = (const char*)A + (size_t)(m0 + srow) * K2 + (size_t)kc * KC * 2 + scol;
  const char* pA1 = pA0 + (size_t)128 * K2;
  const char* pB  = (const char*)W + (size_t)(n0 + srow) * K2 + (size_t)kc * KC * 2 + scol;
  char* const ldsb = &lds[0];

#define STG(t)                                              \
  {                                                         \
    char* d_ = ldsb + (((t) & 1) * 24576) + wave * 1024;    \
    const size_t ko_ = (size_t)(t) * 64;                    \
    gload_lds16(pA0 + ko_, d_);                             \
    gload_lds16(pA1 + ko_, d_ + 8192);                      \
    gload_lds16(pB + ko_, d_ + 16384);                      \
  }

  // swizzled ds_read byte offsets
  const int colx = (kgrp * 16) ^ (((row16 >> 1) & 3) << 4);
  int aoff[4], boff[4];
#pragma unroll
  for (int m = 0; m < 4; m++) aoff[m] = (wm * 64 + m * 16 + row16) * 64 + colx;
#pragma unroll
  for (int n = 0; n < 4; n++) boff[n] = 16384 + (wn * 64 + n * 16 + row16) * 64 + colx;

  f32x4 acc[4][4] = {};
  const int NT = KC >> 5;

  STG(0);
  asm volatile("s_waitcnt vmcnt(0)" ::: "memory");
  __builtin_amdgcn_s_barrier();

  for (int t = 0; t < NT; ++t) {
    const char* bufp = ldsb + ((t & 1) * 24576);
    bf16x8 af[4], bfr[4];
#pragma unroll
    for (int m = 0; m < 4; m++) af[m] = *(const bf16x8*)(bufp + aoff[m]);
#pragma unroll
    for (int n = 0; n < 4; n++) bfr[n] = *(const bf16x8*)(bufp + boff[n]);
    if (t + 1 < NT) STG(t + 1);
    asm volatile("s_waitcnt lgkmcnt(0)" ::: "memory");
    __builtin_amdgcn_sched_barrier(0);
    __builtin_amdgcn_s_setprio(1);
#pragma unroll
    for (int m = 0; m < 4; m++)
#pragma unroll
      for (int n = 0; n < 4; n++)
        acc[m][n] = MFMA_BF16(af[m], bfr[n], acc[m][n]);
    __builtin_amdgcn_s_setprio(0);
    if (t + 1 < NT) asm volatile("s_waitcnt vmcnt(0)" ::: "memory");
    __builtin_amdgcn_s_barrier();
  }
#undef STG

  // epilogue: C row = m0+wm*64+m*16+kgrp*4+r, col = n0+wn*64+n*16+row16
#pragma unroll
  for (int m = 0; m < 4; m++) {
    const int rowb = m0 + wm * 64 + m * 16 + kgrp * 4;
#pragma unroll
    for (int n = 0; n < 4; n++) {
      const int col = n0 + wn * 64 + n * 16 + row16;
#pragma unroll
      for (int r = 0; r < 4; r++) {
        const float v = acc[m][n][r];
        const int rr2 = rowb + r;
        if constexpr (EPI == 0) {
          const int bb = rr2 >> 10, s = rr2 & 1023;
          if (col < 1024) {
            const int hh = col >> 6, d = col & 63;
            qb[(((size_t)(bb * NH_ + hh)) * S_ + s) * HD_ + d] = (bf16_t)(v * 0.125f);
          } else if (col < 2048) {
            const int c = col - 1024, hh = c >> 6, d = c & 63;
            kb[(((size_t)(bb * NH_ + hh)) * S_ + s) * HD_ + d] = (bf16_t)v;
          } else {
            const int c = col - 2048, hh = c >> 6, d = c & 63;
            vtb[(((size_t)(bb * NH_ + hh)) * HD_ + d) * S_ + s] = (bf16_t)v;
          }
        } else if constexpr (EPI == 1) {
          atomicAdd(&fout[(size_t)rr2 * N + col], v);
        } else if constexpr (EPI == 2) {
          bout[(size_t)rr2 * N + col] = (bf16_t)fmaxf(v + bias[col], 0.0f);
        } else if constexpr (EPI == 3) {
          const float vb = v + (kc == 0 ? bias[col] : 0.0f);
          atomicAdd(&fout[(size_t)rr2 * N + col], vb);
        } else {
          fout[(size_t)rr2 * N + col] = v + bias[col];
        }
      }
    }
  }
}

// ---------------------------------------------------------------------------
// Flash attention (causal). grid 1024 (XCD-swizzled), 256 thr = 4 waves.
// sP is wave-private -> no __syncthreads in the KV loop (intra-wave lgkmcnt
// ordering suffices). 16 q-tile blocks of one head stay on one XCD's L2.
// ---------------------------------------------------------------------------
__global__ __launch_bounds__(256) void attn_flash(const bf16_t* __restrict__ qg,
                                                  const bf16_t* __restrict__ kg,
                                                  const bf16_t* __restrict__ vtg,
                                                  bf16_t* __restrict__ aout) {
  const int nb = gridDim.x;
  const int logical = ((blockIdx.x & 7) * (nb >> 3)) + (blockIdx.x >> 3);
  const int qtile = logical & 15;  // 0..15
  const int bh    = logical >> 4;  // 0..63
  const int tid = threadIdx.x;
  const int wave = tid >> 6, lane = tid & 63;
  const int row16 = lane & 15, kgrp = lane >> 4;
  const int q0 = qtile * 64 + wave * 16;

  const bf16_t* qb = qg + (size_t)bh * S_ * HD_;
  const bf16_t* kb = kg + (size_t)bh * S_ * HD_;
  const bf16_t* vb = vtg + (size_t)bh * HD_ * S_;

  const bf16x8 qf0 = *(const bf16x8*)&qb[(size_t)(q0 + row16) * HD_ + kgrp * 8];
  const bf16x8 qf1 = *(const bf16x8*)&qb[(size_t)(q0 + row16) * HD_ + 32 + kgrp * 8];

  f32x4 accO[4] = {};
  float mrun[4] = {-1e30f, -1e30f, -1e30f, -1e30f};
  float lrun[4] = {0.f, 0.f, 0.f, 0.f};

  __shared__ bf16_t sP[4][16][32];

  const int kv_end = qtile * 64 + 64;
  for (int k0 = 0; k0 < kv_end; k0 += 32) {
    f32x4 sc0 = {}, sc1 = {};
    {
      bf16x8 kf0 = *(const bf16x8*)&kb[(size_t)(k0 + row16) * HD_ + kgrp * 8];
      bf16x8 kf1 = *(const bf16x8*)&kb[(size_t)(k0 + row16) * HD_ + 32 + kgrp * 8];
      sc0 = MFMA_BF16(qf0, kf0, sc0);
      sc0 = MFMA_BF16(qf1, kf1, sc0);
      bf16x8 kf2 = *(const bf16x8*)&kb[(size_t)(k0 + 16 + row16) * HD_ + kgrp * 8];
      bf16x8 kf3 = *(const bf16x8*)&kb[(size_t)(k0 + 16 + row16) * HD_ + 32 + kgrp * 8];
      sc1 = MFMA_BF16(qf0, kf2, sc1);
      sc1 = MFMA_BF16(qf1, kf3, sc1);
    }
    float p0[4], p1[4];
#pragma unroll
    for (int r = 0; r < 4; r++) {
      const int qglob = q0 + kgrp * 4 + r;
      float s0 = (k0 + row16 <= qglob) ? sc0[r] : -1e30f;
      float s1 = (k0 + 16 + row16 <= qglob) ? sc1[r] : -1e30f;
      float t = fmaxf(s0, s1);
#pragma unroll
      for (int msk = 1; msk < 16; msk <<= 1) t = fmaxf(t, __shfl_xor(t, msk, 64));
      const float mnew  = fmaxf(mrun[r], t);
      const float alpha = __expf(mrun[r] - mnew);
      const float e0 = __expf(s0 - mnew);
      const float e1 = __expf(s1 - mnew);
      float ls = e0 + e1;
#pragma unroll
      for (int msk = 1; msk < 16; msk <<= 1) ls += __shfl_xor(ls, msk, 64);
      lrun[r] = lrun[r] * alpha + ls;
      mrun[r] = mnew;
#pragma unroll
      for (int d = 0; d < 4; d++) accO[d][r] *= alpha;
      p0[r] = e0; p1[r] = e1;
    }
    // P: C-layout -> A-fragment layout via wave-private LDS tile (no barrier)
#pragma unroll
    for (int r = 0; r < 4; r++) {
      sP[wave][kgrp * 4 + r][row16]      = (bf16_t)p0[r];
      sP[wave][kgrp * 4 + r][16 + row16] = (bf16_t)p1[r];
    }
    const bf16x8 pf = *(const bf16x8*)&sP[wave][row16][kgrp * 8];
#pragma unroll
    for (int d = 0; d < 4; d++) {
      bf16x8 vf = *(const bf16x8*)&vb[(size_t)(d * 16 + row16) * S_ + k0 + kgrp * 8];
      accO[d] = MFMA_BF16(pf, vf, accO[d]);
    }
  }

  const int b = bh >> 4, hh = bh & 15;
#pragma unroll
  for (int d = 0; d < 4; d++)
#pragma unroll
    for (int r = 0; r < 4; r++) {
      const int tok = b * S_ + q0 + kgrp * 4 + r;
      aout[(size_t)tok * D_ + hh * HD_ + d * 16 + row16] = (bf16_t)(accO[d][r] / lrun[r]);
    }
}

// ---------------------------------------------------------------------------
// Launch
// ---------------------------------------------------------------------------
extern "C" void kernel_launch(void* const* d_in, const int* in_sizes, int n_in,
                              void* d_out, int out_size, void* d_ws, size_t ws_size,
                              hipStream_t stream) {
  const int*   x      = (const int*)d_in[0];
  const float* emb_W  = (const float*)d_in[1];
  const float* q_W    = (const float*)d_in[2];
  const float* k_W    = (const float*)d_in[3];
  const float* v_W    = (const float*)d_in[4];
  const float* o_W    = (const float*)d_in[5];
  const float* ln0_g  = (const float*)d_in[6];
  const float* ln0_b  = (const float*)d_in[7];
  const float* ln1_g  = (const float*)d_in[8];
  const float* ln1_b  = (const float*)d_in[9];
  const float* ffn_W1 = (const float*)d_in[10];
  const float* ffn_b1 = (const float*)d_in[11];
  const float* ffn_W2 = (const float*)d_in[12];
  const float* ffn_b2 = (const float*)d_in[13];
  const float* out_W  = (const float*)d_in[14];
  const float* out_b  = (const float*)d_in[15];
  float* out = (float*)d_out;

  char* p = (char*)d_ws;
  auto take = [&](size_t n) { char* r = p; p += (n + 255) & ~(size_t)255; return r; };
  float*  pe    = (float*)take((size_t)S_ * D_ * 4);
  float*  h     = (float*)take((size_t)TOK_ * D_ * 4);
  bf16_t* ain   = (bf16_t*)take((size_t)TOK_ * D_ * 2);
  bf16_t* attno = (bf16_t*)take((size_t)TOK_ * D_ * 2);
  bf16_t* qb    = (bf16_t*)take((size_t)B_ * NH_ * S_ * HD_ * 2);
  bf16_t* kb    = (bf16_t*)take((size_t)B_ * NH_ * S_ * HD_ * 2);
  bf16_t* vtb   = (bf16_t*)take((size_t)B_ * NH_ * S_ * HD_ * 2);
  bf16_t* ff    = (bf16_t*)take((size_t)TOK_ * HF_ * 2);
  bf16_t* qkvW  = (bf16_t*)take((size_t)3 * D_ * D_ * 2);
  bf16_t* oWb   = (bf16_t*)take((size_t)D_ * D_ * 2);
  bf16_t* W1b   = (bf16_t*)take((size_t)HF_ * D_ * 2);
  bf16_t* W2b   = (bf16_t*)take((size_t)D_ * HF_ * 2);
  bf16_t* outWb = (bf16_t*)take((size_t)V_ * D_ * 2);

  // --- weights -> bf16 ---
  cvt_f32_bf16<<<1024, 256, 0, stream>>>(q_W, qkvW, D_ * D_ / 4);
  cvt_f32_bf16<<<1024, 256, 0, stream>>>(k_W, qkvW + (size_t)D_ * D_, D_ * D_ / 4);
  cvt_f32_bf16<<<1024, 256, 0, stream>>>(v_W, qkvW + (size_t)2 * D_ * D_, D_ * D_ / 4);
  cvt_f32_bf16<<<1024, 256, 0, stream>>>(o_W, oWb, D_ * D_ / 4);
  cvt_f32_bf16<<<4096, 256, 0, stream>>>(ffn_W1, W1b, HF_ * D_ / 4);
  cvt_f32_bf16<<<4096, 256, 0, stream>>>(ffn_W2, W2b, D_ * HF_ / 4);
  cvt_f32_bf16<<<32000, 256, 0, stream>>>(out_W, outWb, V_ * D_ / 4);

  // --- embedding + PE ---
  pe_kernel<<<S_, 256, 0, stream>>>(pe);
  embed_kernel<<<TOK_ * D_ / 4 / 256, 256, 0, stream>>>(x, emb_W, pe, h);

  // --- transformer blocks (shared weights) ---
  for (int blk = 0; blk < 4; blk++) {
    ln_res_kernel<<<TOK_, 256, 0, stream>>>(h, ln0_g, ln0_b, ain);
    gemm_pipe<0, 1><<<16 * (3 * D_ / 128), 512, 0, stream>>>(
        ain, qkvW, 3 * D_, D_, nullptr, nullptr, nullptr, qb, kb, vtb);
    attn_flash<<<16 * B_ * NH_, 256, 0, stream>>>(qb, kb, vtb, attno);
    gemm_pipe<1, 4><<<16 * (D_ / 128) * 4, 512, 0, stream>>>(
        attno, oWb, D_, D_, h, nullptr, nullptr, nullptr, nullptr, nullptr);
    ln_res_kernel<<<TOK_, 256, 0, stream>>>(h, ln1_g, ln1_b, ain);
    gemm_pipe<2, 1><<<16 * (HF_ / 128), 512, 0, stream>>>(
        ain, W1b, HF_, D_, nullptr, ffn_b1, ff, nullptr, nullptr, nullptr);
    gemm_pipe<3, 4><<<16 * (D_ / 128) * 4, 512, 0, stream>>>(
        ff, W2b, D_, HF_, h, ffn_b2, nullptr, nullptr, nullptr, nullptr);
  }

  // --- final logits ---
  cvt_f32_bf16<<<4096, 256, 0, stream>>>(h, ain, TOK_ * D_ / 4);
  gemm_pipe<4, 1><<<16 * (V_ / 128), 512, 0, stream>>>(
      ain, outWb, V_, D_, out, out_b, nullptr, nullptr, nullptr, nullptr);
}

// Round 8
// 1907.102 us; speedup vs baseline: 1.0210x; 1.0210x over previous
//
#include <hip/hip_runtime.h>
#include <hip/hip_bf16.h>
#include <math.h>

// ---------------------------------------------------------------------------
// Types
// ---------------------------------------------------------------------------
typedef __bf16 bf16_t;
typedef __bf16 bf16x8 __attribute__((ext_vector_type(8)));
typedef __bf16 bf16x4 __attribute__((ext_vector_type(4)));
typedef float  f32x4  __attribute__((ext_vector_type(4)));

#define MFMA_BF16(a, b, c) __builtin_amdgcn_mfma_f32_16x16x32_bf16((a), (b), (c), 0, 0, 0)

typedef const void __attribute__((address_space(1)))* gas_ptr;
typedef void       __attribute__((address_space(3)))* las_ptr;

__device__ __forceinline__ void gload_lds16(const void* g, void* l) {
  // global -> LDS direct, 16B per lane. LDS dest is wave-uniform base + lane*16.
  __builtin_amdgcn_global_load_lds((gas_ptr)g, (las_ptr)l, 16, 0, 0);
}

// ---------------------------------------------------------------------------
// Model constants
// ---------------------------------------------------------------------------
static constexpr int B_ = 4, S_ = 1024, D_ = 1024, HF_ = 4096, V_ = 32000;
static constexpr int NH_ = 16, HD_ = 64;
static constexpr int TOK_ = B_ * S_;  // 4096

// ---------------------------------------------------------------------------
// fp32 -> bf16 conversion (vectorized x4)
// ---------------------------------------------------------------------------
__global__ __launch_bounds__(256) void cvt_f32_bf16(const float* __restrict__ in,
                                                    bf16_t* __restrict__ out, int n4) {
  int i = blockIdx.x * 256 + threadIdx.x;
  if (i < n4) {
    float4 v = ((const float4*)in)[i];
    bf16x4 o;
    o[0] = (bf16_t)v.x; o[1] = (bf16_t)v.y; o[2] = (bf16_t)v.z; o[3] = (bf16_t)v.w;
    ((bf16x4*)out)[i] = o;
  }
}

// ---------------------------------------------------------------------------
// Sinusoidal positional encoding table
// ---------------------------------------------------------------------------
__global__ __launch_bounds__(256) void pe_kernel(float* __restrict__ pe) {
  const int s = blockIdx.x;
  for (int i = threadIdx.x; i < D_ / 2; i += 256) {
    float div = expf((2.0f * (float)i) * (-9.210340371976184f / (float)D_)); // ln(10000)
    float a = (float)s * div;
    pe[(size_t)s * D_ + 2 * i]     = sinf(a);
    pe[(size_t)s * D_ + 2 * i + 1] = cosf(a);
  }
}

// ---------------------------------------------------------------------------
// Embedding: h[t][d] = emb_W[x[t]][d] * 32 + pe[t % S][d]
// ---------------------------------------------------------------------------
__global__ __launch_bounds__(256) void embed_kernel(const int* __restrict__ x,
                                                    const float* __restrict__ embW,
                                                    const float* __restrict__ pe,
                                                    float* __restrict__ h) {
  int i = blockIdx.x * 256 + threadIdx.x;
  int token = i >> 8;
  int c4 = i & 255;
  int idx = x[token];
  float4 e = ((const float4*)(embW + (size_t)idx * D_))[c4];
  float4 p = ((const float4*)(pe + (size_t)(token & (S_ - 1)) * D_))[c4];
  float4 o;
  o.x = e.x * 32.0f + p.x; o.y = e.y * 32.0f + p.y;
  o.z = e.z * 32.0f + p.z; o.w = e.w * 32.0f + p.w;
  ((float4*)(h + (size_t)token * D_))[c4] = o;
}

// ---------------------------------------------------------------------------
// a_in = h + LayerNorm(h)*g + b   -> bf16
// ---------------------------------------------------------------------------
__global__ __launch_bounds__(256) void ln_res_kernel(const float* __restrict__ h,
                                                     const float* __restrict__ gamma,
                                                     const float* __restrict__ beta,
                                                     bf16_t* __restrict__ out) {
  const int row = blockIdx.x;
  const int tid = threadIdx.x;
  const float4 v = ((const float4*)(h + (size_t)row * D_))[tid];
  float s  = v.x + v.y + v.z + v.w;
  float s2 = v.x * v.x + v.y * v.y + v.z * v.z + v.w * v.w;
#pragma unroll
  for (int m = 1; m < 64; m <<= 1) {
    s  += __shfl_xor(s, m, 64);
    s2 += __shfl_xor(s2, m, 64);
  }
  __shared__ float red[2][4];
  const int wave = tid >> 6, lane = tid & 63;
  if (lane == 0) { red[0][wave] = s; red[1][wave] = s2; }
  __syncthreads();
  s  = red[0][0] + red[0][1] + red[0][2] + red[0][3];
  s2 = red[1][0] + red[1][1] + red[1][2] + red[1][3];
  const float mu   = s * (1.0f / D_);
  const float rstd = rsqrtf(s2 * (1.0f / D_) - mu * mu + 1e-5f);
  const float4 g4 = ((const float4*)gamma)[tid];
  const float4 b4 = ((const float4*)beta)[tid];
  bf16x4 o;
  o[0] = (bf16_t)(v.x + (v.x - mu) * rstd * g4.x + b4.x);
  o[1] = (bf16_t)(v.y + (v.y - mu) * rstd * g4.y + b4.y);
  o[2] = (bf16_t)(v.z + (v.z - mu) * rstd * g4.z + b4.z);
  o[3] = (bf16_t)(v.w + (v.w - mu) * rstd * g4.w + b4.w);
  ((bf16x4*)(out + (size_t)row * D_))[tid] = o;
}

// ---------------------------------------------------------------------------
// 8-phase pipelined GEMM (m201-derived): C[4096,N] = A[4096,K] @ W[N,K]^T.
// BM=BN=256, BK=64, 8 waves (2M x 4N), 2 x 64 KB LDS dbuf.
// Phases per K-tile t: P0(m03,n01) P1(m03,n23) P2(m47,n23) P3(m47,n01).
// Stage one quarter-unit (2 gloads/wave) per phase:
//   P0 -> A.m47(t+1), P1 -> B.n23(t+1), P2 -> A.m03(t+2), P3 -> B.n01(t+2)
// WAIT PLACEMENT (the r7 bug fix): each vmcnt sits AFTER the phase's MFMA and
// BEFORE the phase-end barrier; the barrier makes the per-wave wait collective
// so the NEXT phase's ds_reads are safe. FIFO accounting (2 loads/unit/wave):
//   end-P0: vmcnt(6)  drains AM47(t), BN23(t)     (protects P1+P2 reads)
//   end-P3: vmcnt(8)  drains AM03(t+1), BN01(t+1) (protects next P0 reads)
//   tails:  end-P0@NT-1 vmcnt(0); end-P3@NT-2 vmcnt(4); never 0 mid-loop.
// Prologue: 6 units then vmcnt(8)+barrier before first read.
// Swizzle: 128B rows, byte col ^ ((row&7)<<4), involution (pre-swizzled global
// src, linear gload dest, swizzled ds_read) - 0 conflicts measured r3-r6.
// M-fastest block order + bijective XCD swizzle (grid % 8 == 0).
// Epilogues: 0 QKV-scatter, 2 bias+relu->bf16, 4 bias->f32.
// ---------------------------------------------------------------------------
template <int EPI>
__global__ __launch_bounds__(512, 1) void gemm_pipe(
    const bf16_t* __restrict__ A, const bf16_t* __restrict__ W, int N, int K,
    float* __restrict__ fout, const float* __restrict__ bias, bf16_t* __restrict__ bout,
    bf16_t* __restrict__ qb, bf16_t* __restrict__ kb, bf16_t* __restrict__ vtb) {
  __shared__ char lds[2][65536];  // per buf: A 32 KB (256r x 128B) | B 32 KB

  const int tid = threadIdx.x;
  const int wave = tid >> 6, lane = tid & 63;
  const int row16 = lane & 15, kgrp = lane >> 4;
  const int wm = wave >> 2, wn = wave & 3;  // 2M x 4N wave grid

  // block swizzle: XCD-bijective (grid % 8 == 0), then M-fastest (16 M-tiles)
  const int nb = gridDim.x;
  const int logical = (blockIdx.x & 7) * (nb >> 3) + (blockIdx.x >> 3);
  const int m0 = (logical & 15) << 8;
  const int n0 = (logical >> 4) << 8;
  const size_t K2 = (size_t)K * 2;

  // ---- staging addresses (inverse-swizzled global src, linear LDS dest) ----
  const int lr = lane >> 3;                         // 0..7 row within wave span
  const int swz = ((lane & 7) * 16) ^ (lr << 4);    // byte col in 128B row
  const int rA = wave * 8 + lr;                     // 0..63
  const char* gAr = (const char*)A + (size_t)(m0 + rA) * K2 + swz;
  const int rB = (wave < 4 ? wave * 8 : 64 + (wave - 4) * 8) + lr;
  const char* gBr = (const char*)W + (size_t)(n0 + rB) * K2 + swz;
  char* const ldsc = &lds[0][0];
  const int dAw = wave * 1024;
  const int dBw = 32768 + (wave < 4 ? wave * 1024 : 8192 + (wave - 4) * 1024);

#define STG_AM03(v)                                                     \
  { char* d_ = ldsc + (((v) & 1) << 16) + dAw;                          \
    const char* g_ = gAr + (size_t)(v) * 128;                           \
    gload_lds16(g_, d_); gload_lds16(g_ + 128 * K2, d_ + 16384); }
#define STG_AM47(v)                                                     \
  { char* d_ = ldsc + (((v) & 1) << 16) + dAw + 8192;                   \
    const char* g_ = gAr + (size_t)(v) * 128 + 64 * K2;                 \
    gload_lds16(g_, d_); gload_lds16(g_ + 128 * K2, d_ + 16384); }
#define STG_BN01(v)                                                     \
  { char* d_ = ldsc + (((v) & 1) << 16) + dBw;                          \
    const char* g_ = gBr + (size_t)(v) * 128;                           \
    gload_lds16(g_, d_); gload_lds16(g_ + 128 * K2, d_ + 16384); }
#define STG_BN23(v)                                                     \
  { char* d_ = ldsc + (((v) & 1) << 16) + dBw + 4096;                   \
    const char* g_ = gBr + (size_t)(v) * 128 + 32 * K2;                 \
    gload_lds16(g_, d_); gload_lds16(g_ + 128 * K2, d_ + 16384); }

  // ---- swizzled ds_read bases ----
  const int colx0 = (kgrp * 16) ^ ((row16 & 7) << 4);
  const int colx1 = (64 + kgrp * 16) ^ ((row16 & 7) << 4);
  const int aA0 = (wm * 128 + row16) * 128 + colx0;
  const int aA1 = (wm * 128 + row16) * 128 + colx1;
  const int bA0 = 32768 + (wn * 64 + row16) * 128 + colx0;
  const int bA1 = 32768 + (wn * 64 + row16) * 128 + colx1;

#define LD_A(mh)                                                          \
  _Pragma("unroll") for (int m_ = 0; m_ < 4; m_++) {                      \
    af[m_][0] = *(const bf16x8*)(bufp + aA0 + (mh) * 8192 + m_ * 2048);   \
    af[m_][1] = *(const bf16x8*)(bufp + aA1 + (mh) * 8192 + m_ * 2048);   \
  }
#define LD_B(BF, nh)                                                      \
  _Pragma("unroll") for (int n_ = 0; n_ < 2; n_++) {                      \
    BF[n_][0] = *(const bf16x8*)(bufp + bA0 + (nh) * 4096 + n_ * 2048);   \
    BF[n_][1] = *(const bf16x8*)(bufp + bA1 + (nh) * 4096 + n_ * 2048);   \
  }
#define GATE()                                        \
  __builtin_amdgcn_s_barrier();                       \
  asm volatile("s_waitcnt lgkmcnt(0)" ::: "memory");  \
  __builtin_amdgcn_sched_barrier(0);
#define PH_MFMA(MB, NB, BF)                                                    \
  __builtin_amdgcn_s_setprio(1);                                               \
  _Pragma("unroll") for (int kh_ = 0; kh_ < 2; kh_++)                          \
    _Pragma("unroll") for (int m_ = 0; m_ < 4; m_++)                           \
      _Pragma("unroll") for (int n_ = 0; n_ < 2; n_++)                         \
          acc[(MB) + m_][(NB) + n_] =                                          \
              MFMA_BF16(af[m_][kh_], BF[n_][kh_], acc[(MB) + m_][(NB) + n_]);  \
  __builtin_amdgcn_s_setprio(0);

  f32x4 acc[8][4] = {};
  bf16x8 af[4][2], bfA[2][2], bfB[2][2];
  const int NT = K >> 6;

  // prologue: tile 0 fully + tile 1's {A.m03, B.n01} (12 loads), then make
  // AM03(0)+BN01(0) collectively visible BEFORE any ds_read (r7 bug fix).
  STG_AM03(0); STG_BN01(0); STG_AM47(0); STG_BN23(0);
  if (NT > 1) { STG_AM03(1); STG_BN01(1); }
  if (NT > 1) { asm volatile("s_waitcnt vmcnt(8)" ::: "memory"); }
  else        { asm volatile("s_waitcnt vmcnt(4)" ::: "memory"); }
  __builtin_amdgcn_s_barrier();

  for (int t = 0; t < NT; ++t) {
    const char* bufp = ldsc + ((t & 1) << 16);
    // ---- P0: (m03, n01) ----
    LD_A(0);
    LD_B(bfA, 0);
    if (t + 1 < NT) STG_AM47(t + 1);
    GATE();
    PH_MFMA(0, 0, bfA);
    if (t + 1 < NT) { asm volatile("s_waitcnt vmcnt(6)" ::: "memory"); }
    else            { asm volatile("s_waitcnt vmcnt(0)" ::: "memory"); }
    __builtin_amdgcn_s_barrier();  // AM47(t), BN23(t) collectively visible
    // ---- P1: (m03, n23) ----
    LD_B(bfB, 1);
    if (t + 1 < NT) STG_BN23(t + 1);
    GATE();
    PH_MFMA(0, 2, bfB);
    __builtin_amdgcn_s_barrier();
    // ---- P2: (m47, n23) ----
    LD_A(1);
    if (t + 2 < NT) STG_AM03(t + 2);
    GATE();
    PH_MFMA(4, 2, bfB);
    __builtin_amdgcn_s_barrier();
    // ---- P3: (m47, n01) ---- (no ds_read; af=m47, bfA=n01 both live)
    if (t + 2 < NT) STG_BN01(t + 2);
    __builtin_amdgcn_s_barrier();
    __builtin_amdgcn_sched_barrier(0);
    PH_MFMA(4, 0, bfA);
    if (t + 2 < NT)      { asm volatile("s_waitcnt vmcnt(8)" ::: "memory"); }
    else if (t + 1 < NT) { asm volatile("s_waitcnt vmcnt(4)" ::: "memory"); }
    __builtin_amdgcn_s_barrier();  // AM03(t+1), BN01(t+1) collectively visible
  }
#undef STG_AM03
#undef STG_AM47
#undef STG_BN01
#undef STG_BN23
#undef LD_A
#undef LD_B
#undef GATE
#undef PH_MFMA

  // epilogue: C row = m0+wm*128+m*16+kgrp*4+r, col = n0+wn*64+n*16+row16
#pragma unroll
  for (int m = 0; m < 8; m++) {
    const int rowb = m0 + wm * 128 + m * 16 + kgrp * 4;
#pragma unroll
    for (int n = 0; n < 4; n++) {
      const int col = n0 + wn * 64 + n * 16 + row16;
#pragma unroll
      for (int r = 0; r < 4; r++) {
        const float v = acc[m][n][r];
        const int rr2 = rowb + r;
        if constexpr (EPI == 0) {
          const int bb = rr2 >> 10, s = rr2 & 1023;
          if (col < 1024) {
            const int hh = col >> 6, d = col & 63;
            qb[(((size_t)(bb * NH_ + hh)) * S_ + s) * HD_ + d] = (bf16_t)(v * 0.125f);
          } else if (col < 2048) {
            const int c = col - 1024, hh = c >> 6, d = c & 63;
            kb[(((size_t)(bb * NH_ + hh)) * S_ + s) * HD_ + d] = (bf16_t)v;
          } else {
            const int c = col - 2048, hh = c >> 6, d = c & 63;
            vtb[(((size_t)(bb * NH_ + hh)) * HD_ + d) * S_ + s] = (bf16_t)v;
          }
        } else if constexpr (EPI == 2) {
          bout[(size_t)rr2 * N + col] = (bf16_t)fmaxf(v + bias[col], 0.0f);
        } else {
          fout[(size_t)rr2 * N + col] = v + bias[col];
        }
      }
    }
  }
}

// ---------------------------------------------------------------------------
// m97-structure GEMM (N=1024 shapes: O-proj EPI=1, FFN2 EPI=3) - deterministic
// ---------------------------------------------------------------------------
template <int EPI>
__global__ __launch_bounds__(256) void gemm_bt(
    const bf16_t* __restrict__ A, const bf16_t* __restrict__ W, int M, int N, int K,
    float* __restrict__ fout, const float* __restrict__ bias) {
  __shared__ bf16_t sA[128 * 32];
  __shared__ bf16_t sB[128 * 32];
  const int tid = threadIdx.x;
  const int wave = tid >> 6, lane = tid & 63;
  const int row16 = lane & 15, kgrp = lane >> 4;
  const int m0 = blockIdx.y * 128, n0 = blockIdx.x * 128;
  const int wr = wave >> 1, wc = wave & 1;

  const int srow  = lane >> 2;
  const int skoff = (lane & 3) * 8;
  const bf16_t* gA = A + (size_t)(m0 + wave * 32 + srow) * K + skoff;
  const bf16_t* gB = W + (size_t)(n0 + wave * 32 + srow) * K + skoff;
  bf16_t* lA0 = &sA[(wave * 2 + 0) * 512];
  bf16_t* lA1 = &sA[(wave * 2 + 1) * 512];
  bf16_t* lB0 = &sB[(wave * 2 + 0) * 512];
  bf16_t* lB1 = &sB[(wave * 2 + 1) * 512];

  f32x4 acc[4][4] = {};

  for (int k0 = 0; k0 < K; k0 += 32) {
    gload_lds16(gA + k0, lA0);
    gload_lds16(gA + k0 + (size_t)16 * K, lA1);
    gload_lds16(gB + k0, lB0);
    gload_lds16(gB + k0 + (size_t)16 * K, lB1);
    __syncthreads();
    bf16x8 af[4], bfr[4];
#pragma unroll
    for (int m = 0; m < 4; m++)
      af[m] = *(const bf16x8*)&sA[(wr * 64 + m * 16 + row16) * 32 + kgrp * 8];
#pragma unroll
    for (int n = 0; n < 4; n++)
      bfr[n] = *(const bf16x8*)&sB[(wc * 64 + n * 16 + row16) * 32 + kgrp * 8];
#pragma unroll
    for (int m = 0; m < 4; m++)
#pragma unroll
      for (int n = 0; n < 4; n++)
        acc[m][n] = MFMA_BF16(af[m], bfr[n], acc[m][n]);
    __syncthreads();
  }

#pragma unroll
  for (int m = 0; m < 4; m++) {
    const int rowb = m0 + wr * 64 + m * 16 + kgrp * 4;
#pragma unroll
    for (int n = 0; n < 4; n++) {
      const int col = n0 + wc * 64 + n * 16 + row16;
#pragma unroll
      for (int r = 0; r < 4; r++) {
        const float v = acc[m][n][r];
        const int rr = rowb + r;
        if constexpr (EPI == 1) {
          fout[(size_t)rr * N + col] += v;
        } else {
          fout[(size_t)rr * N + col] += v + bias[col];
        }
      }
    }
  }
}

// ---------------------------------------------------------------------------
// Flash attention (causal). grid 1024 (XCD-swizzled), 256 thr = 4 waves.
// sP is wave-private -> no __syncthreads in the KV loop.
// ---------------------------------------------------------------------------
__global__ __launch_bounds__(256) void attn_flash(const bf16_t* __restrict__ qg,
                                                  const bf16_t* __restrict__ kg,
                                                  const bf16_t* __restrict__ vtg,
                                                  bf16_t* __restrict__ aout) {
  const int nb = gridDim.x;
  const int logical = ((blockIdx.x & 7) * (nb >> 3)) + (blockIdx.x >> 3);
  const int qtile = logical & 15;
  const int bh    = logical >> 4;
  const int tid = threadIdx.x;
  const int wave = tid >> 6, lane = tid & 63;
  const int row16 = lane & 15, kgrp = lane >> 4;
  const int q0 = qtile * 64 + wave * 16;

  const bf16_t* qb = qg + (size_t)bh * S_ * HD_;
  const bf16_t* kb = kg + (size_t)bh * S_ * HD_;
  const bf16_t* vb = vtg + (size_t)bh * HD_ * S_;

  const bf16x8 qf0 = *(const bf16x8*)&qb[(size_t)(q0 + row16) * HD_ + kgrp * 8];
  const bf16x8 qf1 = *(const bf16x8*)&qb[(size_t)(q0 + row16) * HD_ + 32 + kgrp * 8];

  f32x4 accO[4] = {};
  float mrun[4] = {-1e30f, -1e30f, -1e30f, -1e30f};
  float lrun[4] = {0.f, 0.f, 0.f, 0.f};

  __shared__ bf16_t sP[4][16][32];

  const int kv_end = qtile * 64 + 64;
  for (int k0 = 0; k0 < kv_end; k0 += 32) {
    f32x4 sc0 = {}, sc1 = {};
    {
      bf16x8 kf0 = *(const bf16x8*)&kb[(size_t)(k0 + row16) * HD_ + kgrp * 8];
      bf16x8 kf1 = *(const bf16x8*)&kb[(size_t)(k0 + row16) * HD_ + 32 + kgrp * 8];
      sc0 = MFMA_BF16(qf0, kf0, sc0);
      sc0 = MFMA_BF16(qf1, kf1, sc0);
      bf16x8 kf2 = *(const bf16x8*)&kb[(size_t)(k0 + 16 + row16) * HD_ + kgrp * 8];
      bf16x8 kf3 = *(const bf16x8*)&kb[(size_t)(k0 + 16 + row16) * HD_ + 32 + kgrp * 8];
      sc1 = MFMA_BF16(qf0, kf2, sc1);
      sc1 = MFMA_BF16(qf1, kf3, sc1);
    }
    float p0[4], p1[4];
#pragma unroll
    for (int r = 0; r < 4; r++) {
      const int qglob = q0 + kgrp * 4 + r;
      float s0 = (k0 + row16 <= qglob) ? sc0[r] : -1e30f;
      float s1 = (k0 + 16 + row16 <= qglob) ? sc1[r] : -1e30f;
      float t = fmaxf(s0, s1);
#pragma unroll
      for (int msk = 1; msk < 16; msk <<= 1) t = fmaxf(t, __shfl_xor(t, msk, 64));
      const float mnew  = fmaxf(mrun[r], t);
      const float alpha = __expf(mrun[r] - mnew);
      const float e0 = __expf(s0 - mnew);
      const float e1 = __expf(s1 - mnew);
      float ls = e0 + e1;
#pragma unroll
      for (int msk = 1; msk < 16; msk <<= 1) ls += __shfl_xor(ls, msk, 64);
      lrun[r] = lrun[r] * alpha + ls;
      mrun[r] = mnew;
#pragma unroll
      for (int d = 0; d < 4; d++) accO[d][r] *= alpha;
      p0[r] = e0; p1[r] = e1;
    }
#pragma unroll
    for (int r = 0; r < 4; r++) {
      sP[wave][kgrp * 4 + r][row16]      = (bf16_t)p0[r];
      sP[wave][kgrp * 4 + r][16 + row16] = (bf16_t)p1[r];
    }
    const bf16x8 pf = *(const bf16x8*)&sP[wave][row16][kgrp * 8];
#pragma unroll
    for (int d = 0; d < 4; d++) {
      bf16x8 vf = *(const bf16x8*)&vb[(size_t)(d * 16 + row16) * S_ + k0 + kgrp * 8];
      accO[d] = MFMA_BF16(pf, vf, accO[d]);
    }
  }

  const int b = bh >> 4, hh = bh & 15;
#pragma unroll
  for (int d = 0; d < 4; d++)
#pragma unroll
    for (int r = 0; r < 4; r++) {
      const int tok = b * S_ + q0 + kgrp * 4 + r;
      aout[(size_t)tok * D_ + hh * HD_ + d * 16 + row16] = (bf16_t)(accO[d][r] / lrun[r]);
    }
}

// ---------------------------------------------------------------------------
// Launch
// ---------------------------------------------------------------------------
extern "C" void kernel_launch(void* const* d_in, const int* in_sizes, int n_in,
                              void* d_out, int out_size, void* d_ws, size_t ws_size,
                              hipStream_t stream) {
  const int*   x      = (const int*)d_in[0];
  const float* emb_W  = (const float*)d_in[1];
  const float* q_W    = (const float*)d_in[2];
  const float* k_W    = (const float*)d_in[3];
  const float* v_W    = (const float*)d_in[4];
  const float* o_W    = (const float*)d_in[5];
  const float* ln0_g  = (const float*)d_in[6];
  const float* ln0_b  = (const float*)d_in[7];
  const float* ln1_g  = (const float*)d_in[8];
  const float* ln1_b  = (const float*)d_in[9];
  const float* ffn_W1 = (const float*)d_in[10];
  const float* ffn_b1 = (const float*)d_in[11];
  const float* ffn_W2 = (const float*)d_in[12];
  const float* ffn_b2 = (const float*)d_in[13];
  const float* out_W  = (const float*)d_in[14];
  const float* out_b  = (const float*)d_in[15];
  float* out = (float*)d_out;

  char* p = (char*)d_ws;
  auto take = [&](size_t n) { char* r = p; p += (n + 255) & ~(size_t)255; return r; };
  float*  pe    = (float*)take((size_t)S_ * D_ * 4);
  float*  h     = (float*)take((size_t)TOK_ * D_ * 4);
  bf16_t* ain   = (bf16_t*)take((size_t)TOK_ * D_ * 2);
  bf16_t* attno = (bf16_t*)take((size_t)TOK_ * D_ * 2);
  bf16_t* qb    = (bf16_t*)take((size_t)B_ * NH_ * S_ * HD_ * 2);
  bf16_t* kb    = (bf16_t*)take((size_t)B_ * NH_ * S_ * HD_ * 2);
  bf16_t* vtb   = (bf16_t*)take((size_t)B_ * NH_ * S_ * HD_ * 2);
  bf16_t* ff    = (bf16_t*)take((size_t)TOK_ * HF_ * 2);
  bf16_t* qkvW  = (bf16_t*)take((size_t)3 * D_ * D_ * 2);
  bf16_t* oWb   = (bf16_t*)take((size_t)D_ * D_ * 2);
  bf16_t* W1b   = (bf16_t*)take((size_t)HF_ * D_ * 2);
  bf16_t* W2b   = (bf16_t*)take((size_t)D_ * HF_ * 2);
  bf16_t* outWb = (bf16_t*)take((size_t)V_ * D_ * 2);

  // --- weights -> bf16 ---
  cvt_f32_bf16<<<1024, 256, 0, stream>>>(q_W, qkvW, D_ * D_ / 4);
  cvt_f32_bf16<<<1024, 256, 0, stream>>>(k_W, qkvW + (size_t)D_ * D_, D_ * D_ / 4);
  cvt_f32_bf16<<<1024, 256, 0, stream>>>(v_W, qkvW + (size_t)2 * D_ * D_, D_ * D_ / 4);
  cvt_f32_bf16<<<1024, 256, 0, stream>>>(o_W, oWb, D_ * D_ / 4);
  cvt_f32_bf16<<<4096, 256, 0, stream>>>(ffn_W1, W1b, HF_ * D_ / 4);
  cvt_f32_bf16<<<4096, 256, 0, stream>>>(ffn_W2, W2b, D_ * HF_ / 4);
  cvt_f32_bf16<<<32000, 256, 0, stream>>>(out_W, outWb, V_ * D_ / 4);

  // --- embedding + PE ---
  pe_kernel<<<S_, 256, 0, stream>>>(pe);
  embed_kernel<<<TOK_ * D_ / 4 / 256, 256, 0, stream>>>(x, emb_W, pe, h);

  // --- transformer blocks (shared weights) ---
  for (int blk = 0; blk < 4; blk++) {
    ln_res_kernel<<<TOK_, 256, 0, stream>>>(h, ln0_g, ln0_b, ain);
    gemm_pipe<0><<<16 * (3 * D_ / 256), 512, 0, stream>>>(
        ain, qkvW, 3 * D_, D_, nullptr, nullptr, nullptr, qb, kb, vtb);
    attn_flash<<<16 * B_ * NH_, 256, 0, stream>>>(qb, kb, vtb, attno);
    gemm_bt<1><<<dim3(D_ / 128, TOK_ / 128), 256, 0, stream>>>(
        attno, oWb, TOK_, D_, D_, h, nullptr);
    ln_res_kernel<<<TOK_, 256, 0, stream>>>(h, ln1_g, ln1_b, ain);
    gemm_pipe<2><<<16 * (HF_ / 256), 512, 0, stream>>>(
        ain, W1b, HF_, D_, nullptr, ffn_b1, ff, nullptr, nullptr, nullptr);
    gemm_bt<3><<<dim3(D_ / 128, TOK_ / 128), 256, 0, stream>>>(
        ff, W2b, TOK_, D_, HF_, h, ffn_b2);
  }

  // --- final logits ---
  cvt_f32_bf16<<<4096, 256, 0, stream>>>(h, ain, TOK_ * D_ / 4);
  gemm_pipe<4><<<16 * (V_ / 256), 512, 0, stream>>>(
      ain, outWb, V_, D_, out, out_b, nullptr, nullptr, nullptr, nullptr);
}

// Round 9
// 1810.479 us; speedup vs baseline: 1.0755x; 1.0534x over previous
//
#include <hip/hip_runtime.h>
#include <hip/hip_bf16.h>
#include <math.h>

// ---------------------------------------------------------------------------
// Types
// ---------------------------------------------------------------------------
typedef __bf16 bf16_t;
typedef __bf16 bf16x8 __attribute__((ext_vector_type(8)));
typedef __bf16 bf16x4 __attribute__((ext_vector_type(4)));
typedef float  f32x4  __attribute__((ext_vector_type(4)));

#define MFMA_BF16(a, b, c) __builtin_amdgcn_mfma_f32_16x16x32_bf16((a), (b), (c), 0, 0, 0)

typedef const void __attribute__((address_space(1)))* gas_ptr;
typedef void       __attribute__((address_space(3)))* las_ptr;

__device__ __forceinline__ void gload_lds16(const void* g, void* l) {
  // global -> LDS direct, 16B per lane. LDS dest is wave-uniform base + lane*16.
  __builtin_amdgcn_global_load_lds((gas_ptr)g, (las_ptr)l, 16, 0, 0);
}

// ---------------------------------------------------------------------------
// Model constants
// ---------------------------------------------------------------------------
static constexpr int B_ = 4, S_ = 1024, D_ = 1024, HF_ = 4096, V_ = 32000;
static constexpr int NH_ = 16, HD_ = 64;
static constexpr int TOK_ = B_ * S_;  // 4096

// ---------------------------------------------------------------------------
// fp32 -> bf16 conversion (vectorized x4)
// ---------------------------------------------------------------------------
__global__ __launch_bounds__(256) void cvt_f32_bf16(const float* __restrict__ in,
                                                    bf16_t* __restrict__ out, int n4) {
  int i = blockIdx.x * 256 + threadIdx.x;
  if (i < n4) {
    float4 v = ((const float4*)in)[i];
    bf16x4 o;
    o[0] = (bf16_t)v.x; o[1] = (bf16_t)v.y; o[2] = (bf16_t)v.z; o[3] = (bf16_t)v.w;
    ((bf16x4*)out)[i] = o;
  }
}

// ---------------------------------------------------------------------------
// Sinusoidal positional encoding table
// ---------------------------------------------------------------------------
__global__ __launch_bounds__(256) void pe_kernel(float* __restrict__ pe) {
  const int s = blockIdx.x;
  for (int i = threadIdx.x; i < D_ / 2; i += 256) {
    float div = expf((2.0f * (float)i) * (-9.210340371976184f / (float)D_)); // ln(10000)
    float a = (float)s * div;
    pe[(size_t)s * D_ + 2 * i]     = sinf(a);
    pe[(size_t)s * D_ + 2 * i + 1] = cosf(a);
  }
}

// ---------------------------------------------------------------------------
// Embedding: h[t][d] = emb_W[x[t]][d] * 32 + pe[t % S][d]
// ---------------------------------------------------------------------------
__global__ __launch_bounds__(256) void embed_kernel(const int* __restrict__ x,
                                                    const float* __restrict__ embW,
                                                    const float* __restrict__ pe,
                                                    float* __restrict__ h) {
  int i = blockIdx.x * 256 + threadIdx.x;
  int token = i >> 8;
  int c4 = i & 255;
  int idx = x[token];
  float4 e = ((const float4*)(embW + (size_t)idx * D_))[c4];
  float4 p = ((const float4*)(pe + (size_t)(token & (S_ - 1)) * D_))[c4];
  float4 o;
  o.x = e.x * 32.0f + p.x; o.y = e.y * 32.0f + p.y;
  o.z = e.z * 32.0f + p.z; o.w = e.w * 32.0f + p.w;
  ((float4*)(h + (size_t)token * D_))[c4] = o;
}

// ---------------------------------------------------------------------------
// a_in = h + LayerNorm(h)*g + b   -> bf16
// ---------------------------------------------------------------------------
__global__ __launch_bounds__(256) void ln_res_kernel(const float* __restrict__ h,
                                                     const float* __restrict__ gamma,
                                                     const float* __restrict__ beta,
                                                     bf16_t* __restrict__ out) {
  const int row = blockIdx.x;
  const int tid = threadIdx.x;
  const float4 v = ((const float4*)(h + (size_t)row * D_))[tid];
  float s  = v.x + v.y + v.z + v.w;
  float s2 = v.x * v.x + v.y * v.y + v.z * v.z + v.w * v.w;
#pragma unroll
  for (int m = 1; m < 64; m <<= 1) {
    s  += __shfl_xor(s, m, 64);
    s2 += __shfl_xor(s2, m, 64);
  }
  __shared__ float red[2][4];
  const int wave = tid >> 6, lane = tid & 63;
  if (lane == 0) { red[0][wave] = s; red[1][wave] = s2; }
  __syncthreads();
  s  = red[0][0] + red[0][1] + red[0][2] + red[0][3];
  s2 = red[1][0] + red[1][1] + red[1][2] + red[1][3];
  const float mu   = s * (1.0f / D_);
  const float rstd = rsqrtf(s2 * (1.0f / D_) - mu * mu + 1e-5f);
  const float4 g4 = ((const float4*)gamma)[tid];
  const float4 b4 = ((const float4*)beta)[tid];
  bf16x4 o;
  o[0] = (bf16_t)(v.x + (v.x - mu) * rstd * g4.x + b4.x);
  o[1] = (bf16_t)(v.y + (v.y - mu) * rstd * g4.y + b4.y);
  o[2] = (bf16_t)(v.z + (v.z - mu) * rstd * g4.z + b4.z);
  o[3] = (bf16_t)(v.w + (v.w - mu) * rstd * g4.w + b4.w);
  ((bf16x4*)(out + (size_t)row * D_))[tid] = o;
}

// ---------------------------------------------------------------------------
// 8-phase pipelined GEMM (verified r8): C[4096,N] = A[4096,K] @ W[N,K]^T.
// BM=BN=256, BK=64, 8 waves (2M x 4N), 2 x 64 KB LDS dbuf.
// Waits: end-P0 vmcnt(6), end-P3 vmcnt(8); tails NT-1 end-P0 vmcnt(0),
// NT-2 end-P3 vmcnt(4). Prologue 6 units -> vmcnt(8)+barrier.
// Swizzle: 128B rows, byte ^ ((row&7)<<4), involution. M-fastest + XCD.
// Epilogues: 0 QKV-scatter, 2 bias+relu->bf16, 4 bias->f32.
// ---------------------------------------------------------------------------
template <int EPI>
__global__ __launch_bounds__(512, 1) void gemm_pipe(
    const bf16_t* __restrict__ A, const bf16_t* __restrict__ W, int N, int K,
    float* __restrict__ fout, const float* __restrict__ bias, bf16_t* __restrict__ bout,
    bf16_t* __restrict__ qb, bf16_t* __restrict__ kb, bf16_t* __restrict__ vtb) {
  __shared__ char lds[2][65536];  // per buf: A 32 KB (256r x 128B) | B 32 KB

  const int tid = threadIdx.x;
  const int wave = tid >> 6, lane = tid & 63;
  const int row16 = lane & 15, kgrp = lane >> 4;
  const int wm = wave >> 2, wn = wave & 3;  // 2M x 4N wave grid

  const int nb = gridDim.x;
  const int logical = (blockIdx.x & 7) * (nb >> 3) + (blockIdx.x >> 3);
  const int m0 = (logical & 15) << 8;
  const int n0 = (logical >> 4) << 8;
  const size_t K2 = (size_t)K * 2;

  const int lr = lane >> 3;
  const int swz = ((lane & 7) * 16) ^ (lr << 4);
  const int rA = wave * 8 + lr;
  const char* gAr = (const char*)A + (size_t)(m0 + rA) * K2 + swz;
  const int rB = (wave < 4 ? wave * 8 : 64 + (wave - 4) * 8) + lr;
  const char* gBr = (const char*)W + (size_t)(n0 + rB) * K2 + swz;
  char* const ldsc = &lds[0][0];
  const int dAw = wave * 1024;
  const int dBw = 32768 + (wave < 4 ? wave * 1024 : 8192 + (wave - 4) * 1024);

#define STG_AM03(v)                                                     \
  { char* d_ = ldsc + (((v) & 1) << 16) + dAw;                          \
    const char* g_ = gAr + (size_t)(v) * 128;                           \
    gload_lds16(g_, d_); gload_lds16(g_ + 128 * K2, d_ + 16384); }
#define STG_AM47(v)                                                     \
  { char* d_ = ldsc + (((v) & 1) << 16) + dAw + 8192;                   \
    const char* g_ = gAr + (size_t)(v) * 128 + 64 * K2;                 \
    gload_lds16(g_, d_); gload_lds16(g_ + 128 * K2, d_ + 16384); }
#define STG_BN01(v)                                                     \
  { char* d_ = ldsc + (((v) & 1) << 16) + dBw;                          \
    const char* g_ = gBr + (size_t)(v) * 128;                           \
    gload_lds16(g_, d_); gload_lds16(g_ + 128 * K2, d_ + 16384); }
#define STG_BN23(v)                                                     \
  { char* d_ = ldsc + (((v) & 1) << 16) + dBw + 4096;                   \
    const char* g_ = gBr + (size_t)(v) * 128 + 32 * K2;                 \
    gload_lds16(g_, d_); gload_lds16(g_ + 128 * K2, d_ + 16384); }

  const int colx0 = (kgrp * 16) ^ ((row16 & 7) << 4);
  const int colx1 = (64 + kgrp * 16) ^ ((row16 & 7) << 4);
  const int aA0 = (wm * 128 + row16) * 128 + colx0;
  const int aA1 = (wm * 128 + row16) * 128 + colx1;
  const int bA0 = 32768 + (wn * 64 + row16) * 128 + colx0;
  const int bA1 = 32768 + (wn * 64 + row16) * 128 + colx1;

#define LD_A(mh)                                                          \
  _Pragma("unroll") for (int m_ = 0; m_ < 4; m_++) {                      \
    af[m_][0] = *(const bf16x8*)(bufp + aA0 + (mh) * 8192 + m_ * 2048);   \
    af[m_][1] = *(const bf16x8*)(bufp + aA1 + (mh) * 8192 + m_ * 2048);   \
  }
#define LD_B(BF, nh)                                                      \
  _Pragma("unroll") for (int n_ = 0; n_ < 2; n_++) {                      \
    BF[n_][0] = *(const bf16x8*)(bufp + bA0 + (nh) * 4096 + n_ * 2048);   \
    BF[n_][1] = *(const bf16x8*)(bufp + bA1 + (nh) * 4096 + n_ * 2048);   \
  }
#define GATE()                                        \
  __builtin_amdgcn_s_barrier();                       \
  asm volatile("s_waitcnt lgkmcnt(0)" ::: "memory");  \
  __builtin_amdgcn_sched_barrier(0);
#define PH_MFMA(MB, NB, BF)                                                    \
  __builtin_amdgcn_s_setprio(1);                                               \
  _Pragma("unroll") for (int kh_ = 0; kh_ < 2; kh_++)                          \
    _Pragma("unroll") for (int m_ = 0; m_ < 4; m_++)                           \
      _Pragma("unroll") for (int n_ = 0; n_ < 2; n_++)                         \
          acc[(MB) + m_][(NB) + n_] =                                          \
              MFMA_BF16(af[m_][kh_], BF[n_][kh_], acc[(MB) + m_][(NB) + n_]);  \
  __builtin_amdgcn_s_setprio(0);

  f32x4 acc[8][4] = {};
  bf16x8 af[4][2], bfA[2][2], bfB[2][2];
  const int NT = K >> 6;

  STG_AM03(0); STG_BN01(0); STG_AM47(0); STG_BN23(0);
  if (NT > 1) { STG_AM03(1); STG_BN01(1); }
  if (NT > 1) { asm volatile("s_waitcnt vmcnt(8)" ::: "memory"); }
  else        { asm volatile("s_waitcnt vmcnt(4)" ::: "memory"); }
  __builtin_amdgcn_s_barrier();

  for (int t = 0; t < NT; ++t) {
    const char* bufp = ldsc + ((t & 1) << 16);
    // ---- P0: (m03, n01) ----
    LD_A(0);
    LD_B(bfA, 0);
    if (t + 1 < NT) STG_AM47(t + 1);
    GATE();
    PH_MFMA(0, 0, bfA);
    if (t + 1 < NT) { asm volatile("s_waitcnt vmcnt(6)" ::: "memory"); }
    else            { asm volatile("s_waitcnt vmcnt(0)" ::: "memory"); }
    __builtin_amdgcn_s_barrier();
    // ---- P1: (m03, n23) ----
    LD_B(bfB, 1);
    if (t + 1 < NT) STG_BN23(t + 1);
    GATE();
    PH_MFMA(0, 2, bfB);
    __builtin_amdgcn_s_barrier();
    // ---- P2: (m47, n23) ----
    LD_A(1);
    if (t + 2 < NT) STG_AM03(t + 2);
    GATE();
    PH_MFMA(4, 2, bfB);
    __builtin_amdgcn_s_barrier();
    // ---- P3: (m47, n01) ----
    if (t + 2 < NT) STG_BN01(t + 2);
    __builtin_amdgcn_s_barrier();
    __builtin_amdgcn_sched_barrier(0);
    PH_MFMA(4, 0, bfA);
    if (t + 2 < NT)      { asm volatile("s_waitcnt vmcnt(8)" ::: "memory"); }
    else if (t + 1 < NT) { asm volatile("s_waitcnt vmcnt(4)" ::: "memory"); }
    __builtin_amdgcn_s_barrier();
  }
#undef STG_AM03
#undef STG_AM47
#undef STG_BN01
#undef STG_BN23
#undef LD_A
#undef LD_B
#undef GATE
#undef PH_MFMA

#pragma unroll
  for (int m = 0; m < 8; m++) {
    const int rowb = m0 + wm * 128 + m * 16 + kgrp * 4;
#pragma unroll
    for (int n = 0; n < 4; n++) {
      const int col = n0 + wn * 64 + n * 16 + row16;
#pragma unroll
      for (int r = 0; r < 4; r++) {
        const float v = acc[m][n][r];
        const int rr2 = rowb + r;
        if constexpr (EPI == 0) {
          const int bb = rr2 >> 10, s = rr2 & 1023;
          if (col < 1024) {
            const int hh = col >> 6, d = col & 63;
            qb[(((size_t)(bb * NH_ + hh)) * S_ + s) * HD_ + d] = (bf16_t)(v * 0.125f);
          } else if (col < 2048) {
            const int c = col - 1024, hh = c >> 6, d = c & 63;
            kb[(((size_t)(bb * NH_ + hh)) * S_ + s) * HD_ + d] = (bf16_t)v;
          } else {
            const int c = col - 2048, hh = c >> 6, d = c & 63;
            vtb[(((size_t)(bb * NH_ + hh)) * HD_ + d) * S_ + s] = (bf16_t)v;
          }
        } else if constexpr (EPI == 2) {
          bout[(size_t)rr2 * N + col] = (bf16_t)fmaxf(v + bias[col], 0.0f);
        } else {
          fout[(size_t)rr2 * N + col] = v + bias[col];
        }
      }
    }
  }
}

// ---------------------------------------------------------------------------
// m97-structure GEMM (N=1024 shapes: O-proj EPI=1, FFN2 EPI=3) - deterministic
// ---------------------------------------------------------------------------
template <int EPI>
__global__ __launch_bounds__(256) void gemm_bt(
    const bf16_t* __restrict__ A, const bf16_t* __restrict__ W, int M, int N, int K,
    float* __restrict__ fout, const float* __restrict__ bias) {
  __shared__ bf16_t sA[128 * 32];
  __shared__ bf16_t sB[128 * 32];
  const int tid = threadIdx.x;
  const int wave = tid >> 6, lane = tid & 63;
  const int row16 = lane & 15, kgrp = lane >> 4;
  const int m0 = blockIdx.y * 128, n0 = blockIdx.x * 128;
  const int wr = wave >> 1, wc = wave & 1;

  const int srow  = lane >> 2;
  const int skoff = (lane & 3) * 8;
  const bf16_t* gA = A + (size_t)(m0 + wave * 32 + srow) * K + skoff;
  const bf16_t* gB = W + (size_t)(n0 + wave * 32 + srow) * K + skoff;
  bf16_t* lA0 = &sA[(wave * 2 + 0) * 512];
  bf16_t* lA1 = &sA[(wave * 2 + 1) * 512];
  bf16_t* lB0 = &sB[(wave * 2 + 0) * 512];
  bf16_t* lB1 = &sB[(wave * 2 + 1) * 512];

  f32x4 acc[4][4] = {};

  for (int k0 = 0; k0 < K; k0 += 32) {
    gload_lds16(gA + k0, lA0);
    gload_lds16(gA + k0 + (size_t)16 * K, lA1);
    gload_lds16(gB + k0, lB0);
    gload_lds16(gB + k0 + (size_t)16 * K, lB1);
    __syncthreads();
    bf16x8 af[4], bfr[4];
#pragma unroll
    for (int m = 0; m < 4; m++)
      af[m] = *(const bf16x8*)&sA[(wr * 64 + m * 16 + row16) * 32 + kgrp * 8];
#pragma unroll
    for (int n = 0; n < 4; n++)
      bfr[n] = *(const bf16x8*)&sB[(wc * 64 + n * 16 + row16) * 32 + kgrp * 8];
#pragma unroll
    for (int m = 0; m < 4; m++)
#pragma unroll
      for (int n = 0; n < 4; n++)
        acc[m][n] = MFMA_BF16(af[m], bfr[n], acc[m][n]);
    __syncthreads();
  }

#pragma unroll
  for (int m = 0; m < 4; m++) {
    const int rowb = m0 + wr * 64 + m * 16 + kgrp * 4;
#pragma unroll
    for (int n = 0; n < 4; n++) {
      const int col = n0 + wc * 64 + n * 16 + row16;
#pragma unroll
      for (int r = 0; r < 4; r++) {
        const float v = acc[m][n][r];
        const int rr = rowb + r;
        if constexpr (EPI == 1) {
          fout[(size_t)rr * N + col] += v;
        } else {
          fout[(size_t)rr * N + col] += v + bias[col];
        }
      }
    }
  }
}

// ---------------------------------------------------------------------------
// Flash attention (causal), KVBLK=64, latency-pipelined.
// grid 1024 (XCD-swizzled), 256 thr = 4 waves, each wave 16 q-rows.
// K(t+1) fragments prefetched after softmax(t) (loop-carried regs);
// V(t) issued right after QK(t) so its latency hides under softmax.
// Diagonal-only masking (wave-uniform branch). sP XOR-swizzled
// (byte ^ (row&7)<<4 on both write and read) -> conflict-free b128 reads.
// ---------------------------------------------------------------------------
__global__ __launch_bounds__(256, 3) void attn_flash(const bf16_t* __restrict__ qg,
                                                     const bf16_t* __restrict__ kg,
                                                     const bf16_t* __restrict__ vtg,
                                                     bf16_t* __restrict__ aout) {
  const int nb = gridDim.x;
  const int logical = ((blockIdx.x & 7) * (nb >> 3)) + (blockIdx.x >> 3);
  const int qtile = logical & 15;   // 0..15
  const int bh    = logical >> 4;   // 0..63
  const int tid = threadIdx.x;
  const int wave = tid >> 6, lane = tid & 63;
  const int row16 = lane & 15, kgrp = lane >> 4;
  const int q0 = qtile * 64 + wave * 16;

  const bf16_t* qb = qg + (size_t)bh * S_ * HD_;
  const bf16_t* kb = kg + (size_t)bh * S_ * HD_;
  const bf16_t* vb = vtg + (size_t)bh * HD_ * S_;

  const bf16x8 qf0 = *(const bf16x8*)&qb[(size_t)(q0 + row16) * HD_ + kgrp * 8];
  const bf16x8 qf1 = *(const bf16x8*)&qb[(size_t)(q0 + row16) * HD_ + 32 + kgrp * 8];

  f32x4 accO[4] = {};
  float mrun[4] = {-1e30f, -1e30f, -1e30f, -1e30f};
  float lrun[4] = {0.f, 0.f, 0.f, 0.f};

  __shared__ char sP[4][2048];  // per wave: 16 rows x 128 B (swizzled)
  char* const sw = &sP[wave][0];

  const int NTt = qtile + 1;  // 64-wide KV tiles (uniform across waves)

  // preload K fragments for tile 0
  bf16x8 kf[4][2];
#pragma unroll
  for (int q = 0; q < 4; q++) {
    kf[q][0] = *(const bf16x8*)&kb[(size_t)(q * 16 + row16) * HD_ + kgrp * 8];
    kf[q][1] = *(const bf16x8*)&kb[(size_t)(q * 16 + row16) * HD_ + 32 + kgrp * 8];
  }

  for (int t = 0; t < NTt; ++t) {
    const int k0 = t * 64;
    // ---- QK^T: 4 quadrants x (2 k-halves) ----
    f32x4 sc[4];
#pragma unroll
    for (int q = 0; q < 4; q++) {
      f32x4 z = {};
      z = MFMA_BF16(qf0, kf[q][0], z);
      sc[q] = MFMA_BF16(qf1, kf[q][1], z);
    }
    // ---- V early-issue (consumed after softmax; latency hidden) ----
    bf16x8 vf[4][2];
#pragma unroll
    for (int d = 0; d < 4; d++) {
      vf[d][0] = *(const bf16x8*)&vb[(size_t)(d * 16 + row16) * S_ + k0 + kgrp * 8];
      vf[d][1] = *(const bf16x8*)&vb[(size_t)(d * 16 + row16) * S_ + k0 + 32 + kgrp * 8];
    }
    // ---- online softmax over 64 columns ----
    const bool diag = (k0 + 64 > q0);  // wave-uniform
    float p[4][4];
#pragma unroll
    for (int r = 0; r < 4; r++) {
      const int qglob = q0 + kgrp * 4 + r;
      float s0 = sc[0][r], s1 = sc[1][r], s2 = sc[2][r], s3 = sc[3][r];
      if (diag) {
        s0 = (k0 + row16 <= qglob) ? s0 : -1e30f;
        s1 = (k0 + 16 + row16 <= qglob) ? s1 : -1e30f;
        s2 = (k0 + 32 + row16 <= qglob) ? s2 : -1e30f;
        s3 = (k0 + 48 + row16 <= qglob) ? s3 : -1e30f;
      }
      float tmax = fmaxf(fmaxf(s0, s1), fmaxf(s2, s3));
#pragma unroll
      for (int msk = 1; msk < 16; msk <<= 1) tmax = fmaxf(tmax, __shfl_xor(tmax, msk, 64));
      const float mnew  = fmaxf(mrun[r], tmax);
      const float alpha = __expf(mrun[r] - mnew);
      const float e0 = __expf(s0 - mnew);
      const float e1 = __expf(s1 - mnew);
      const float e2 = __expf(s2 - mnew);
      const float e3 = __expf(s3 - mnew);
      float ls = (e0 + e1) + (e2 + e3);
#pragma unroll
      for (int msk = 1; msk < 16; msk <<= 1) ls += __shfl_xor(ls, msk, 64);
      lrun[r] = lrun[r] * alpha + ls;
      mrun[r] = mnew;
#pragma unroll
      for (int d = 0; d < 4; d++) accO[d][r] *= alpha;
      p[r][0] = e0; p[r][1] = e1; p[r][2] = e2; p[r][3] = e3;
    }
    // ---- prefetch K(t+1) while P-transpose + PV run ----
    if (t + 1 < NTt) {
      const int k0n = k0 + 64;
#pragma unroll
      for (int q = 0; q < 4; q++) {
        kf[q][0] = *(const bf16x8*)&kb[(size_t)(k0n + q * 16 + row16) * HD_ + kgrp * 8];
        kf[q][1] = *(const bf16x8*)&kb[(size_t)(k0n + q * 16 + row16) * HD_ + 32 + kgrp * 8];
      }
    }
    // ---- P: C-layout -> A-fragment via swizzled wave-private LDS ----
#pragma unroll
    for (int r = 0; r < 4; r++) {
      const int prow = kgrp * 4 + r;
      const int px = (prow & 7) << 4;
#pragma unroll
      for (int q = 0; q < 4; q++) {
        *(bf16_t*)(sw + prow * 128 + (((q * 16 + row16) * 2) ^ px)) = (bf16_t)p[r][q];
      }
    }
    const int rx = (row16 & 7) << 4;
    const bf16x8 pf0 = *(const bf16x8*)(sw + row16 * 128 + ((kgrp * 16) ^ rx));
    const bf16x8 pf1 = *(const bf16x8*)(sw + row16 * 128 + ((64 + kgrp * 16) ^ rx));
    // ---- PV ----
#pragma unroll
    for (int d = 0; d < 4; d++) {
      accO[d] = MFMA_BF16(pf0, vf[d][0], accO[d]);
      accO[d] = MFMA_BF16(pf1, vf[d][1], accO[d]);
    }
  }

  const int b = bh >> 4, hh = bh & 15;
#pragma unroll
  for (int d = 0; d < 4; d++)
#pragma unroll
    for (int r = 0; r < 4; r++) {
      const int tok = b * S_ + q0 + kgrp * 4 + r;
      aout[(size_t)tok * D_ + hh * HD_ + d * 16 + row16] = (bf16_t)(accO[d][r] / lrun[r]);
    }
}

// ---------------------------------------------------------------------------
// Launch
// ---------------------------------------------------------------------------
extern "C" void kernel_launch(void* const* d_in, const int* in_sizes, int n_in,
                              void* d_out, int out_size, void* d_ws, size_t ws_size,
                              hipStream_t stream) {
  const int*   x      = (const int*)d_in[0];
  const float* emb_W  = (const float*)d_in[1];
  const float* q_W    = (const float*)d_in[2];
  const float* k_W    = (const float*)d_in[3];
  const float* v_W    = (const float*)d_in[4];
  const float* o_W    = (const float*)d_in[5];
  const float* ln0_g  = (const float*)d_in[6];
  const float* ln0_b  = (const float*)d_in[7];
  const float* ln1_g  = (const float*)d_in[8];
  const float* ln1_b  = (const float*)d_in[9];
  const float* ffn_W1 = (const float*)d_in[10];
  const float* ffn_b1 = (const float*)d_in[11];
  const float* ffn_W2 = (const float*)d_in[12];
  const float* ffn_b2 = (const float*)d_in[13];
  const float* out_W  = (const float*)d_in[14];
  const float* out_b  = (const float*)d_in[15];
  float* out = (float*)d_out;

  char* p = (char*)d_ws;
  auto take = [&](size_t n) { char* r = p; p += (n + 255) & ~(size_t)255; return r; };
  float*  pe    = (float*)take((size_t)S_ * D_ * 4);
  float*  h     = (float*)take((size_t)TOK_ * D_ * 4);
  bf16_t* ain   = (bf16_t*)take((size_t)TOK_ * D_ * 2);
  bf16_t* attno = (bf16_t*)take((size_t)TOK_ * D_ * 2);
  bf16_t* qb    = (bf16_t*)take((size_t)B_ * NH_ * S_ * HD_ * 2);
  bf16_t* kb    = (bf16_t*)take((size_t)B_ * NH_ * S_ * HD_ * 2);
  bf16_t* vtb   = (bf16_t*)take((size_t)B_ * NH_ * S_ * HD_ * 2);
  bf16_t* ff    = (bf16_t*)take((size_t)TOK_ * HF_ * 2);
  bf16_t* qkvW  = (bf16_t*)take((size_t)3 * D_ * D_ * 2);
  bf16_t* oWb   = (bf16_t*)take((size_t)D_ * D_ * 2);
  bf16_t* W1b   = (bf16_t*)take((size_t)HF_ * D_ * 2);
  bf16_t* W2b   = (bf16_t*)take((size_t)D_ * HF_ * 2);
  bf16_t* outWb = (bf16_t*)take((size_t)V_ * D_ * 2);

  // --- weights -> bf16 ---
  cvt_f32_bf16<<<1024, 256, 0, stream>>>(q_W, qkvW, D_ * D_ / 4);
  cvt_f32_bf16<<<1024, 256, 0, stream>>>(k_W, qkvW + (size_t)D_ * D_, D_ * D_ / 4);
  cvt_f32_bf16<<<1024, 256, 0, stream>>>(v_W, qkvW + (size_t)2 * D_ * D_, D_ * D_ / 4);
  cvt_f32_bf16<<<1024, 256, 0, stream>>>(o_W, oWb, D_ * D_ / 4);
  cvt_f32_bf16<<<4096, 256, 0, stream>>>(ffn_W1, W1b, HF_ * D_ / 4);
  cvt_f32_bf16<<<4096, 256, 0, stream>>>(ffn_W2, W2b, D_ * HF_ / 4);
  cvt_f32_bf16<<<32000, 256, 0, stream>>>(out_W, outWb, V_ * D_ / 4);

  // --- embedding + PE ---
  pe_kernel<<<S_, 256, 0, stream>>>(pe);
  embed_kernel<<<TOK_ * D_ / 4 / 256, 256, 0, stream>>>(x, emb_W, pe, h);

  // --- transformer blocks (shared weights) ---
  for (int blk = 0; blk < 4; blk++) {
    ln_res_kernel<<<TOK_, 256, 0, stream>>>(h, ln0_g, ln0_b, ain);
    gemm_pipe<0><<<16 * (3 * D_ / 256), 512, 0, stream>>>(
        ain, qkvW, 3 * D_, D_, nullptr, nullptr, nullptr, qb, kb, vtb);
    attn_flash<<<16 * B_ * NH_, 256, 0, stream>>>(qb, kb, vtb, attno);
    gemm_bt<1><<<dim3(D_ / 128, TOK_ / 128), 256, 0, stream>>>(
        attno, oWb, TOK_, D_, D_, h, nullptr);
    ln_res_kernel<<<TOK_, 256, 0, stream>>>(h, ln1_g, ln1_b, ain);
    gemm_pipe<2><<<16 * (HF_ / 256), 512, 0, stream>>>(
        ain, W1b, HF_, D_, nullptr, ffn_b1, ff, nullptr, nullptr, nullptr);
    gemm_bt<3><<<dim3(D_ / 128, TOK_ / 128), 256, 0, stream>>>(
        ff, W2b, TOK_, D_, HF_, h, ffn_b2);
  }

  // --- final logits ---
  cvt_f32_bf16<<<4096, 256, 0, stream>>>(h, ain, TOK_ * D_ / 4);
  gemm_pipe<4><<<16 * (V_ / 256), 512, 0, stream>>>(
      ain, outWb, V_, D_, out, out_b, nullptr, nullptr, nullptr, nullptr);
}

// Round 10
// 1537.231 us; speedup vs baseline: 1.2666x; 1.1778x over previous
//
#include <hip/hip_runtime.h>
#include <hip/hip_bf16.h>
#include <math.h>

// ---------------------------------------------------------------------------
// Types
// ---------------------------------------------------------------------------
typedef __bf16 bf16_t;
typedef __bf16 bf16x8 __attribute__((ext_vector_type(8)));
typedef __bf16 bf16x4 __attribute__((ext_vector_type(4)));
typedef float  f32x4  __attribute__((ext_vector_type(4)));

#define MFMA_BF16(a, b, c) __builtin_amdgcn_mfma_f32_16x16x32_bf16((a), (b), (c), 0, 0, 0)

typedef const void __attribute__((address_space(1)))* gas_ptr;
typedef void       __attribute__((address_space(3)))* las_ptr;

__device__ __forceinline__ void gload_lds16(const void* g, void* l) {
  // global -> LDS direct, 16B per lane. LDS dest is wave-uniform base + lane*16.
  __builtin_amdgcn_global_load_lds((gas_ptr)g, (las_ptr)l, 16, 0, 0);
}

// ---------------------------------------------------------------------------
// Model constants
// ---------------------------------------------------------------------------
static constexpr int B_ = 4, S_ = 1024, D_ = 1024, HF_ = 4096, V_ = 32000;
static constexpr int NH_ = 16, HD_ = 64;
static constexpr int TOK_ = B_ * S_;  // 4096

// ---------------------------------------------------------------------------
// fp32 -> bf16 conversion (vectorized x4)
// ---------------------------------------------------------------------------
__global__ __launch_bounds__(256) void cvt_f32_bf16(const float* __restrict__ in,
                                                    bf16_t* __restrict__ out, int n4) {
  int i = blockIdx.x * 256 + threadIdx.x;
  if (i < n4) {
    float4 v = ((const float4*)in)[i];
    bf16x4 o;
    o[0] = (bf16_t)v.x; o[1] = (bf16_t)v.y; o[2] = (bf16_t)v.z; o[3] = (bf16_t)v.w;
    ((bf16x4*)out)[i] = o;
  }
}

// ---------------------------------------------------------------------------
// Sinusoidal positional encoding table
// ---------------------------------------------------------------------------
__global__ __launch_bounds__(256) void pe_kernel(float* __restrict__ pe) {
  const int s = blockIdx.x;
  for (int i = threadIdx.x; i < D_ / 2; i += 256) {
    float div = expf((2.0f * (float)i) * (-9.210340371976184f / (float)D_)); // ln(10000)
    float a = (float)s * div;
    pe[(size_t)s * D_ + 2 * i]     = sinf(a);
    pe[(size_t)s * D_ + 2 * i + 1] = cosf(a);
  }
}

// ---------------------------------------------------------------------------
// Embedding: h[t][d] = emb_W[x[t]][d] * 32 + pe[t % S][d]
// ---------------------------------------------------------------------------
__global__ __launch_bounds__(256) void embed_kernel(const int* __restrict__ x,
                                                    const float* __restrict__ embW,
                                                    const float* __restrict__ pe,
                                                    float* __restrict__ h) {
  int i = blockIdx.x * 256 + threadIdx.x;
  int token = i >> 8;
  int c4 = i & 255;
  int idx = x[token];
  float4 e = ((const float4*)(embW + (size_t)idx * D_))[c4];
  float4 p = ((const float4*)(pe + (size_t)(token & (S_ - 1)) * D_))[c4];
  float4 o;
  o.x = e.x * 32.0f + p.x; o.y = e.y * 32.0f + p.y;
  o.z = e.z * 32.0f + p.z; o.w = e.w * 32.0f + p.w;
  ((float4*)(h + (size_t)token * D_))[c4] = o;
}

// ---------------------------------------------------------------------------
// a_in = h + LayerNorm(h)*g + b   -> bf16
// ---------------------------------------------------------------------------
__global__ __launch_bounds__(256) void ln_res_kernel(const float* __restrict__ h,
                                                     const float* __restrict__ gamma,
                                                     const float* __restrict__ beta,
                                                     bf16_t* __restrict__ out) {
  const int row = blockIdx.x;
  const int tid = threadIdx.x;
  const float4 v = ((const float4*)(h + (size_t)row * D_))[tid];
  float s  = v.x + v.y + v.z + v.w;
  float s2 = v.x * v.x + v.y * v.y + v.z * v.z + v.w * v.w;
#pragma unroll
  for (int m = 1; m < 64; m <<= 1) {
    s  += __shfl_xor(s, m, 64);
    s2 += __shfl_xor(s2, m, 64);
  }
  __shared__ float red[2][4];
  const int wave = tid >> 6, lane = tid & 63;
  if (lane == 0) { red[0][wave] = s; red[1][wave] = s2; }
  __syncthreads();
  s  = red[0][0] + red[0][1] + red[0][2] + red[0][3];
  s2 = red[1][0] + red[1][1] + red[1][2] + red[1][3];
  const float mu   = s * (1.0f / D_);
  const float rstd = rsqrtf(s2 * (1.0f / D_) - mu * mu + 1e-5f);
  const float4 g4 = ((const float4*)gamma)[tid];
  const float4 b4 = ((const float4*)beta)[tid];
  bf16x4 o;
  o[0] = (bf16_t)(v.x + (v.x - mu) * rstd * g4.x + b4.x);
  o[1] = (bf16_t)(v.y + (v.y - mu) * rstd * g4.y + b4.y);
  o[2] = (bf16_t)(v.z + (v.z - mu) * rstd * g4.z + b4.z);
  o[3] = (bf16_t)(v.w + (v.w - mu) * rstd * g4.w + b4.w);
  ((bf16x4*)(out + (size_t)row * D_))[tid] = o;
}

// ---------------------------------------------------------------------------
// gemm_sq: 128x128 tile, BK=64, 2 phases/K-tile, 2 blocks/CU.
// C[4096,N] = A[4096,K] @ W[N,K]^T. 8 waves (2M x 4N); per-wave 64x32
// (acc[4][2]); wave n-frags straddle both B halves (nf*64 + wn*16).
// LDS 2 x 32 KB dbuf (A 16 KB | B 16 KB per buf); launch_bounds(512,4)
// => <=128 VGPR => 2 blocks/CU; sibling block covers barrier/drain stalls.
// Schedule per tile t: P0{LD_A(8) + LD_B(n01); stage B(t+1); GATE; 8 MFMA;
// barrier} P1{LD_B(n23); stage A(t+2); GATE; 8 MFMA; vmcnt(2); barrier}.
// FIFO (2 loads/unit/wave): prologue A0,B0,A1 -> vmcnt(2); steady end-P1
// vmcnt(2) drains A(t+1),B(t+1); tail t=NT-2 vmcnt(0); t=NT-1 none.
// Region lifetimes verified: B(t+1) staged P0 into buf^1.B (last read P1 of
// t-1, before its end barrier); A(t+2) staged P1 into buf.A (last read P0 of
// t, before end-P0 barrier). Swizzle: 128B rows, byte ^ ((row&7)<<4),
// involution (inverse-swizzled global src, linear gload dest, swizzled
// ds_read). M-fastest (32 consecutive logical = one B panel) + XCD swizzle.
// Epilogues: 0 QKV-scatter, 1 fout+=v, 2 relu(v+bias)->bf16, 3 fout+=v+bias.
// ---------------------------------------------------------------------------
template <int EPI>
__global__ __launch_bounds__(512, 4) void gemm_sq(
    const bf16_t* __restrict__ A, const bf16_t* __restrict__ W, int N, int K,
    float* __restrict__ fout, const float* __restrict__ bias, bf16_t* __restrict__ bout,
    bf16_t* __restrict__ qb, bf16_t* __restrict__ kb, bf16_t* __restrict__ vtb) {
  __shared__ char lds[2][32768];

  const int tid = threadIdx.x;
  const int wave = tid >> 6, lane = tid & 63;
  const int row16 = lane & 15, kgrp = lane >> 4;
  const int wm = wave >> 2, wn = wave & 3;  // 2M x 4N

  const int nb = gridDim.x;  // multiple of 8
  const int logical = (blockIdx.x & 7) * (nb >> 3) + (blockIdx.x >> 3);
  const int m0 = (logical & 31) << 7;   // 32 M-tiles, M fastest
  const int n0 = (logical >> 5) << 7;
  const size_t K2 = (size_t)K * 2;

  // staging: wave w covers rows w*8+lr (unit rows 0-63) and +64 (rows 64-127)
  const int lr = lane >> 3;
  const int swz = ((lane & 7) * 16) ^ (lr << 4);
  const char* gA = (const char*)A + (size_t)(m0 + wave * 8 + lr) * K2 + swz;
  const char* gB = (const char*)W + (size_t)(n0 + wave * 8 + lr) * K2 + swz;
  char* const ldsc = &lds[0][0];
  const int dW = wave * 1024;

#define STG_A(v)                                                  \
  { char* d_ = ldsc + (((v) & 1) << 15) + dW;                     \
    const char* g_ = gA + (size_t)(v) * 128;                      \
    gload_lds16(g_, d_); gload_lds16(g_ + 64 * K2, d_ + 8192); }
#define STG_B(v)                                                  \
  { char* d_ = ldsc + (((v) & 1) << 15) + 16384 + dW;             \
    const char* g_ = gB + (size_t)(v) * 128;                      \
    gload_lds16(g_, d_); gload_lds16(g_ + 64 * K2, d_ + 8192); }

  const int colx0 = (kgrp * 16) ^ ((row16 & 7) << 4);
  const int colx1 = (64 + kgrp * 16) ^ ((row16 & 7) << 4);
  int aoff[4], boff[2];
#pragma unroll
  for (int mf = 0; mf < 4; mf++) aoff[mf] = (wm * 64 + mf * 16 + row16) * 128;
#pragma unroll
  for (int nf = 0; nf < 2; nf++) boff[nf] = 16384 + (nf * 64 + wn * 16 + row16) * 128;

#define GATE()                                        \
  __builtin_amdgcn_s_barrier();                       \
  asm volatile("s_waitcnt lgkmcnt(0)" ::: "memory");  \
  __builtin_amdgcn_sched_barrier(0);

  f32x4 acc[4][2] = {};
  bf16x8 af[4][2], bfr[2];
  const int NT = K >> 6;  // >= 16 for all our shapes

  STG_A(0); STG_B(0); STG_A(1);
  asm volatile("s_waitcnt vmcnt(2)" ::: "memory");  // A(0), B(0) landed
  __builtin_amdgcn_s_barrier();

  for (int t = 0; t < NT; ++t) {
    const char* bufp = ldsc + ((t & 1) << 15);
    // ---- P0: all m x n01 ----
#pragma unroll
    for (int mf = 0; mf < 4; mf++) {
      af[mf][0] = *(const bf16x8*)(bufp + aoff[mf] + colx0);
      af[mf][1] = *(const bf16x8*)(bufp + aoff[mf] + colx1);
    }
    bfr[0] = *(const bf16x8*)(bufp + boff[0] + colx0);
    bfr[1] = *(const bf16x8*)(bufp + boff[0] + colx1);
    if (t + 1 < NT) STG_B(t + 1);
    GATE();
    __builtin_amdgcn_s_setprio(1);
#pragma unroll
    for (int mf = 0; mf < 4; mf++) {
      acc[mf][0] = MFMA_BF16(af[mf][0], bfr[0], acc[mf][0]);
      acc[mf][0] = MFMA_BF16(af[mf][1], bfr[1], acc[mf][0]);
    }
    __builtin_amdgcn_s_setprio(0);
    __builtin_amdgcn_s_barrier();  // end-P0 (B(t) n23 already drained)
    // ---- P1: all m x n23 ----
    bfr[0] = *(const bf16x8*)(bufp + boff[1] + colx0);
    bfr[1] = *(const bf16x8*)(bufp + boff[1] + colx1);
    if (t + 2 < NT) STG_A(t + 2);
    GATE();
    __builtin_amdgcn_s_setprio(1);
#pragma unroll
    for (int mf = 0; mf < 4; mf++) {
      acc[mf][1] = MFMA_BF16(af[mf][0], bfr[0], acc[mf][1]);
      acc[mf][1] = MFMA_BF16(af[mf][1], bfr[1], acc[mf][1]);
    }
    __builtin_amdgcn_s_setprio(0);
    if (t + 2 < NT)      { asm volatile("s_waitcnt vmcnt(2)" ::: "memory"); }
    else if (t + 1 < NT) { asm volatile("s_waitcnt vmcnt(0)" ::: "memory"); }
    __builtin_amdgcn_s_barrier();  // A(t+1), B(t+1) collectively visible
  }
#undef STG_A
#undef STG_B
#undef GATE

  // epilogue: row = m0+wm*64+mf*16+kgrp*4+r, col = n0+nf*64+wn*16+row16
#pragma unroll
  for (int mf = 0; mf < 4; mf++) {
    const int rowb = m0 + wm * 64 + mf * 16 + kgrp * 4;
#pragma unroll
    for (int nf = 0; nf < 2; nf++) {
      const int col = n0 + nf * 64 + wn * 16 + row16;
#pragma unroll
      for (int r = 0; r < 4; r++) {
        const float v = acc[mf][nf][r];
        const int rr2 = rowb + r;
        if constexpr (EPI == 0) {
          const int bb = rr2 >> 10, s = rr2 & 1023;
          if (col < 1024) {
            const int hh = col >> 6, d = col & 63;
            qb[(((size_t)(bb * NH_ + hh)) * S_ + s) * HD_ + d] = (bf16_t)(v * 0.125f);
          } else if (col < 2048) {
            const int c = col - 1024, hh = c >> 6, d = c & 63;
            kb[(((size_t)(bb * NH_ + hh)) * S_ + s) * HD_ + d] = (bf16_t)v;
          } else {
            const int c = col - 2048, hh = c >> 6, d = c & 63;
            vtb[(((size_t)(bb * NH_ + hh)) * HD_ + d) * S_ + s] = (bf16_t)v;
          }
        } else if constexpr (EPI == 1) {
          fout[(size_t)rr2 * N + col] += v;
        } else if constexpr (EPI == 2) {
          bout[(size_t)rr2 * N + col] = (bf16_t)fmaxf(v + bias[col], 0.0f);
        } else {
          fout[(size_t)rr2 * N + col] += v + bias[col];
        }
      }
    }
  }
}

// ---------------------------------------------------------------------------
// 8-phase pipelined GEMM (verified r8) - logits only (EPI=4: bias -> f32).
// BM=BN=256, BK=64, 8 waves, 2 x 64 KB dbuf; counted vmcnt; swizzled.
// ---------------------------------------------------------------------------
template <int EPI>
__global__ __launch_bounds__(512, 1) void gemm_pipe(
    const bf16_t* __restrict__ A, const bf16_t* __restrict__ W, int N, int K,
    float* __restrict__ fout, const float* __restrict__ bias) {
  __shared__ char lds[2][65536];

  const int tid = threadIdx.x;
  const int wave = tid >> 6, lane = tid & 63;
  const int row16 = lane & 15, kgrp = lane >> 4;
  const int wm = wave >> 2, wn = wave & 3;

  const int nb = gridDim.x;
  const int logical = (blockIdx.x & 7) * (nb >> 3) + (blockIdx.x >> 3);
  const int m0 = (logical & 15) << 8;
  const int n0 = (logical >> 4) << 8;
  const size_t K2 = (size_t)K * 2;

  const int lr = lane >> 3;
  const int swz = ((lane & 7) * 16) ^ (lr << 4);
  const int rA = wave * 8 + lr;
  const char* gAr = (const char*)A + (size_t)(m0 + rA) * K2 + swz;
  const int rB = (wave < 4 ? wave * 8 : 64 + (wave - 4) * 8) + lr;
  const char* gBr = (const char*)W + (size_t)(n0 + rB) * K2 + swz;
  char* const ldsc = &lds[0][0];
  const int dAw = wave * 1024;
  const int dBw = 32768 + (wave < 4 ? wave * 1024 : 8192 + (wave - 4) * 1024);

#define STG_AM03(v)                                                     \
  { char* d_ = ldsc + (((v) & 1) << 16) + dAw;                          \
    const char* g_ = gAr + (size_t)(v) * 128;                           \
    gload_lds16(g_, d_); gload_lds16(g_ + 128 * K2, d_ + 16384); }
#define STG_AM47(v)                                                     \
  { char* d_ = ldsc + (((v) & 1) << 16) + dAw + 8192;                   \
    const char* g_ = gAr + (size_t)(v) * 128 + 64 * K2;                 \
    gload_lds16(g_, d_); gload_lds16(g_ + 128 * K2, d_ + 16384); }
#define STG_BN01(v)                                                     \
  { char* d_ = ldsc + (((v) & 1) << 16) + dBw;                          \
    const char* g_ = gBr + (size_t)(v) * 128;                           \
    gload_lds16(g_, d_); gload_lds16(g_ + 128 * K2, d_ + 16384); }
#define STG_BN23(v)                                                     \
  { char* d_ = ldsc + (((v) & 1) << 16) + dBw + 4096;                   \
    const char* g_ = gBr + (size_t)(v) * 128 + 32 * K2;                 \
    gload_lds16(g_, d_); gload_lds16(g_ + 128 * K2, d_ + 16384); }

  const int colx0 = (kgrp * 16) ^ ((row16 & 7) << 4);
  const int colx1 = (64 + kgrp * 16) ^ ((row16 & 7) << 4);
  const int aA0 = (wm * 128 + row16) * 128 + colx0;
  const int aA1 = (wm * 128 + row16) * 128 + colx1;
  const int bA0 = 32768 + (wn * 64 + row16) * 128 + colx0;
  const int bA1 = 32768 + (wn * 64 + row16) * 128 + colx1;

#define LD_A(mh)                                                          \
  _Pragma("unroll") for (int m_ = 0; m_ < 4; m_++) {                      \
    af[m_][0] = *(const bf16x8*)(bufp + aA0 + (mh) * 8192 + m_ * 2048);   \
    af[m_][1] = *(const bf16x8*)(bufp + aA1 + (mh) * 8192 + m_ * 2048);   \
  }
#define LD_B(BF, nh)                                                      \
  _Pragma("unroll") for (int n_ = 0; n_ < 2; n_++) {                      \
    BF[n_][0] = *(const bf16x8*)(bufp + bA0 + (nh) * 4096 + n_ * 2048);   \
    BF[n_][1] = *(const bf16x8*)(bufp + bA1 + (nh) * 4096 + n_ * 2048);   \
  }
#define GATE()                                        \
  __builtin_amdgcn_s_barrier();                       \
  asm volatile("s_waitcnt lgkmcnt(0)" ::: "memory");  \
  __builtin_amdgcn_sched_barrier(0);
#define PH_MFMA(MB, NB, BF)                                                    \
  __builtin_amdgcn_s_setprio(1);                                               \
  _Pragma("unroll") for (int kh_ = 0; kh_ < 2; kh_++)                          \
    _Pragma("unroll") for (int m_ = 0; m_ < 4; m_++)                           \
      _Pragma("unroll") for (int n_ = 0; n_ < 2; n_++)                         \
          acc[(MB) + m_][(NB) + n_] =                                          \
              MFMA_BF16(af[m_][kh_], BF[n_][kh_], acc[(MB) + m_][(NB) + n_]);  \
  __builtin_amdgcn_s_setprio(0);

  f32x4 acc[8][4] = {};
  bf16x8 af[4][2], bfA[2][2], bfB[2][2];
  const int NT = K >> 6;

  STG_AM03(0); STG_BN01(0); STG_AM47(0); STG_BN23(0);
  if (NT > 1) { STG_AM03(1); STG_BN01(1); }
  if (NT > 1) { asm volatile("s_waitcnt vmcnt(8)" ::: "memory"); }
  else        { asm volatile("s_waitcnt vmcnt(4)" ::: "memory"); }
  __builtin_amdgcn_s_barrier();

  for (int t = 0; t < NT; ++t) {
    const char* bufp = ldsc + ((t & 1) << 16);
    LD_A(0);
    LD_B(bfA, 0);
    if (t + 1 < NT) STG_AM47(t + 1);
    GATE();
    PH_MFMA(0, 0, bfA);
    if (t + 1 < NT) { asm volatile("s_waitcnt vmcnt(6)" ::: "memory"); }
    else            { asm volatile("s_waitcnt vmcnt(0)" ::: "memory"); }
    __builtin_amdgcn_s_barrier();
    LD_B(bfB, 1);
    if (t + 1 < NT) STG_BN23(t + 1);
    GATE();
    PH_MFMA(0, 2, bfB);
    __builtin_amdgcn_s_barrier();
    LD_A(1);
    if (t + 2 < NT) STG_AM03(t + 2);
    GATE();
    PH_MFMA(4, 2, bfB);
    __builtin_amdgcn_s_barrier();
    if (t + 2 < NT) STG_BN01(t + 2);
    __builtin_amdgcn_s_barrier();
    __builtin_amdgcn_sched_barrier(0);
    PH_MFMA(4, 0, bfA);
    if (t + 2 < NT)      { asm volatile("s_waitcnt vmcnt(8)" ::: "memory"); }
    else if (t + 1 < NT) { asm volatile("s_waitcnt vmcnt(4)" ::: "memory"); }
    __builtin_amdgcn_s_barrier();
  }
#undef STG_AM03
#undef STG_AM47
#undef STG_BN01
#undef STG_BN23
#undef LD_A
#undef LD_B
#undef GATE
#undef PH_MFMA

#pragma unroll
  for (int m = 0; m < 8; m++) {
    const int rowb = m0 + wm * 128 + m * 16 + kgrp * 4;
#pragma unroll
    for (int n = 0; n < 4; n++) {
      const int col = n0 + wn * 64 + n * 16 + row16;
#pragma unroll
      for (int r = 0; r < 4; r++) {
        fout[(size_t)(rowb + r) * N + col] = acc[m][n][r] + bias[col];
      }
    }
  }
}

// ---------------------------------------------------------------------------
// Flash attention (causal), KVBLK=64, latency-pipelined (verified r9).
// ---------------------------------------------------------------------------
__global__ __launch_bounds__(256, 3) void attn_flash(const bf16_t* __restrict__ qg,
                                                     const bf16_t* __restrict__ kg,
                                                     const bf16_t* __restrict__ vtg,
                                                     bf16_t* __restrict__ aout) {
  const int nb = gridDim.x;
  const int logical = ((blockIdx.x & 7) * (nb >> 3)) + (blockIdx.x >> 3);
  const int qtile = logical & 15;
  const int bh    = logical >> 4;
  const int tid = threadIdx.x;
  const int wave = tid >> 6, lane = tid & 63;
  const int row16 = lane & 15, kgrp = lane >> 4;
  const int q0 = qtile * 64 + wave * 16;

  const bf16_t* qb = qg + (size_t)bh * S_ * HD_;
  const bf16_t* kb = kg + (size_t)bh * S_ * HD_;
  const bf16_t* vb = vtg + (size_t)bh * HD_ * S_;

  const bf16x8 qf0 = *(const bf16x8*)&qb[(size_t)(q0 + row16) * HD_ + kgrp * 8];
  const bf16x8 qf1 = *(const bf16x8*)&qb[(size_t)(q0 + row16) * HD_ + 32 + kgrp * 8];

  f32x4 accO[4] = {};
  float mrun[4] = {-1e30f, -1e30f, -1e30f, -1e30f};
  float lrun[4] = {0.f, 0.f, 0.f, 0.f};

  __shared__ char sP[4][2048];
  char* const sw = &sP[wave][0];

  const int NTt = qtile + 1;

  bf16x8 kf[4][2];
#pragma unroll
  for (int q = 0; q < 4; q++) {
    kf[q][0] = *(const bf16x8*)&kb[(size_t)(q * 16 + row16) * HD_ + kgrp * 8];
    kf[q][1] = *(const bf16x8*)&kb[(size_t)(q * 16 + row16) * HD_ + 32 + kgrp * 8];
  }

  for (int t = 0; t < NTt; ++t) {
    const int k0 = t * 64;
    f32x4 sc[4];
#pragma unroll
    for (int q = 0; q < 4; q++) {
      f32x4 z = {};
      z = MFMA_BF16(qf0, kf[q][0], z);
      sc[q] = MFMA_BF16(qf1, kf[q][1], z);
    }
    bf16x8 vf[4][2];
#pragma unroll
    for (int d = 0; d < 4; d++) {
      vf[d][0] = *(const bf16x8*)&vb[(size_t)(d * 16 + row16) * S_ + k0 + kgrp * 8];
      vf[d][1] = *(const bf16x8*)&vb[(size_t)(d * 16 + row16) * S_ + k0 + 32 + kgrp * 8];
    }
    const bool diag = (k0 + 64 > q0);
    float p[4][4];
#pragma unroll
    for (int r = 0; r < 4; r++) {
      const int qglob = q0 + kgrp * 4 + r;
      float s0 = sc[0][r], s1 = sc[1][r], s2 = sc[2][r], s3 = sc[3][r];
      if (diag) {
        s0 = (k0 + row16 <= qglob) ? s0 : -1e30f;
        s1 = (k0 + 16 + row16 <= qglob) ? s1 : -1e30f;
        s2 = (k0 + 32 + row16 <= qglob) ? s2 : -1e30f;
        s3 = (k0 + 48 + row16 <= qglob) ? s3 : -1e30f;
      }
      float tmax = fmaxf(fmaxf(s0, s1), fmaxf(s2, s3));
#pragma unroll
      for (int msk = 1; msk < 16; msk <<= 1) tmax = fmaxf(tmax, __shfl_xor(tmax, msk, 64));
      const float mnew  = fmaxf(mrun[r], tmax);
      const float alpha = __expf(mrun[r] - mnew);
      const float e0 = __expf(s0 - mnew);
      const float e1 = __expf(s1 - mnew);
      const float e2 = __expf(s2 - mnew);
      const float e3 = __expf(s3 - mnew);
      float ls = (e0 + e1) + (e2 + e3);
#pragma unroll
      for (int msk = 1; msk < 16; msk <<= 1) ls += __shfl_xor(ls, msk, 64);
      lrun[r] = lrun[r] * alpha + ls;
      mrun[r] = mnew;
#pragma unroll
      for (int d = 0; d < 4; d++) accO[d][r] *= alpha;
      p[r][0] = e0; p[r][1] = e1; p[r][2] = e2; p[r][3] = e3;
    }
    if (t + 1 < NTt) {
      const int k0n = k0 + 64;
#pragma unroll
      for (int q = 0; q < 4; q++) {
        kf[q][0] = *(const bf16x8*)&kb[(size_t)(k0n + q * 16 + row16) * HD_ + kgrp * 8];
        kf[q][1] = *(const bf16x8*)&kb[(size_t)(k0n + q * 16 + row16) * HD_ + 32 + kgrp * 8];
      }
    }
#pragma unroll
    for (int r = 0; r < 4; r++) {
      const int prow = kgrp * 4 + r;
      const int px = (prow & 7) << 4;
#pragma unroll
      for (int q = 0; q < 4; q++) {
        *(bf16_t*)(sw + prow * 128 + (((q * 16 + row16) * 2) ^ px)) = (bf16_t)p[r][q];
      }
    }
    const int rx = (row16 & 7) << 4;
    const bf16x8 pf0 = *(const bf16x8*)(sw + row16 * 128 + ((kgrp * 16) ^ rx));
    const bf16x8 pf1 = *(const bf16x8*)(sw + row16 * 128 + ((64 + kgrp * 16) ^ rx));
#pragma unroll
    for (int d = 0; d < 4; d++) {
      accO[d] = MFMA_BF16(pf0, vf[d][0], accO[d]);
      accO[d] = MFMA_BF16(pf1, vf[d][1], accO[d]);
    }
  }

  const int b = bh >> 4, hh = bh & 15;
#pragma unroll
  for (int d = 0; d < 4; d++)
#pragma unroll
    for (int r = 0; r < 4; r++) {
      const int tok = b * S_ + q0 + kgrp * 4 + r;
      aout[(size_t)tok * D_ + hh * HD_ + d * 16 + row16] = (bf16_t)(accO[d][r] / lrun[r]);
    }
}

// ---------------------------------------------------------------------------
// Launch
// ---------------------------------------------------------------------------
extern "C" void kernel_launch(void* const* d_in, const int* in_sizes, int n_in,
                              void* d_out, int out_size, void* d_ws, size_t ws_size,
                              hipStream_t stream) {
  const int*   x      = (const int*)d_in[0];
  const float* emb_W  = (const float*)d_in[1];
  const float* q_W    = (const float*)d_in[2];
  const float* k_W    = (const float*)d_in[3];
  const float* v_W    = (const float*)d_in[4];
  const float* o_W    = (const float*)d_in[5];
  const float* ln0_g  = (const float*)d_in[6];
  const float* ln0_b  = (const float*)d_in[7];
  const float* ln1_g  = (const float*)d_in[8];
  const float* ln1_b  = (const float*)d_in[9];
  const float* ffn_W1 = (const float*)d_in[10];
  const float* ffn_b1 = (const float*)d_in[11];
  const float* ffn_W2 = (const float*)d_in[12];
  const float* ffn_b2 = (const float*)d_in[13];
  const float* out_W  = (const float*)d_in[14];
  const float* out_b  = (const float*)d_in[15];
  float* out = (float*)d_out;

  char* p = (char*)d_ws;
  auto take = [&](size_t n) { char* r = p; p += (n + 255) & ~(size_t)255; return r; };
  float*  pe    = (float*)take((size_t)S_ * D_ * 4);
  float*  h     = (float*)take((size_t)TOK_ * D_ * 4);
  bf16_t* ain   = (bf16_t*)take((size_t)TOK_ * D_ * 2);
  bf16_t* attno = (bf16_t*)take((size_t)TOK_ * D_ * 2);
  bf16_t* qb    = (bf16_t*)take((size_t)B_ * NH_ * S_ * HD_ * 2);
  bf16_t* kb    = (bf16_t*)take((size_t)B_ * NH_ * S_ * HD_ * 2);
  bf16_t* vtb   = (bf16_t*)take((size_t)B_ * NH_ * S_ * HD_ * 2);
  bf16_t* ff    = (bf16_t*)take((size_t)TOK_ * HF_ * 2);
  bf16_t* qkvW  = (bf16_t*)take((size_t)3 * D_ * D_ * 2);
  bf16_t* oWb   = (bf16_t*)take((size_t)D_ * D_ * 2);
  bf16_t* W1b   = (bf16_t*)take((size_t)HF_ * D_ * 2);
  bf16_t* W2b   = (bf16_t*)take((size_t)D_ * HF_ * 2);
  bf16_t* outWb = (bf16_t*)take((size_t)V_ * D_ * 2);

  // --- weights -> bf16 ---
  cvt_f32_bf16<<<1024, 256, 0, stream>>>(q_W, qkvW, D_ * D_ / 4);
  cvt_f32_bf16<<<1024, 256, 0, stream>>>(k_W, qkvW + (size_t)D_ * D_, D_ * D_ / 4);
  cvt_f32_bf16<<<1024, 256, 0, stream>>>(v_W, qkvW + (size_t)2 * D_ * D_, D_ * D_ / 4);
  cvt_f32_bf16<<<1024, 256, 0, stream>>>(o_W, oWb, D_ * D_ / 4);
  cvt_f32_bf16<<<4096, 256, 0, stream>>>(ffn_W1, W1b, HF_ * D_ / 4);
  cvt_f32_bf16<<<4096, 256, 0, stream>>>(ffn_W2, W2b, D_ * HF_ / 4);
  cvt_f32_bf16<<<32000, 256, 0, stream>>>(out_W, outWb, V_ * D_ / 4);

  // --- embedding + PE ---
  pe_kernel<<<S_, 256, 0, stream>>>(pe);
  embed_kernel<<<TOK_ * D_ / 4 / 256, 256, 0, stream>>>(x, emb_W, pe, h);

  // --- transformer blocks (shared weights) ---
  for (int blk = 0; blk < 4; blk++) {
    ln_res_kernel<<<TOK_, 256, 0, stream>>>(h, ln0_g, ln0_b, ain);
    gemm_sq<0><<<32 * (3 * D_ / 128), 512, 0, stream>>>(
        ain, qkvW, 3 * D_, D_, nullptr, nullptr, nullptr, qb, kb, vtb);
    attn_flash<<<16 * B_ * NH_, 256, 0, stream>>>(qb, kb, vtb, attno);
    gemm_sq<1><<<32 * (D_ / 128), 512, 0, stream>>>(
        attno, oWb, D_, D_, h, nullptr, nullptr, nullptr, nullptr, nullptr);
    ln_res_kernel<<<TOK_, 256, 0, stream>>>(h, ln1_g, ln1_b, ain);
    gemm_sq<2><<<32 * (HF_ / 128), 512, 0, stream>>>(
        ain, W1b, HF_, D_, nullptr, ffn_b1, ff, nullptr, nullptr, nullptr);
    gemm_sq<3><<<32 * (D_ / 128), 512, 0, stream>>>(
        ff, W2b, D_, HF_, h, ffn_b2, nullptr, nullptr, nullptr, nullptr);
  }

  // --- final logits ---
  cvt_f32_bf16<<<4096, 256, 0, stream>>>(h, ain, TOK_ * D_ / 4);
  gemm_pipe<4><<<16 * (V_ / 256), 512, 0, stream>>>(
      ain, outWb, V_, D_, out, out_b);
}